// Round 2
// baseline (805.300 us; speedup 1.0000x reference)
//
#include <hip/hip_runtime.h>
#include <hip/hip_bf16.h>
#include <math.h>

#define T 2048
#define HID 5120
#define NH 16
#define D_NOPE 128
#define D_ROPE 64
#define D_V 128
#define Q_LORA 1536
#define KV_LORA 512
#define QK_HD 192
#define KVA_N 576
#define KVA_NP 640
#define N_QB (NH*QK_HD)          // 3072
#define N_KVB (NH*(D_NOPE+D_V))  // 4096
#define ATT_SCALE 0.07216878364870322f  // 192^-0.5

typedef __bf16 bf16x8_t __attribute__((ext_vector_type(8)));
typedef float f32x4_t __attribute__((ext_vector_type(4)));
typedef unsigned short u16x4 __attribute__((ext_vector_type(4)));
typedef unsigned int u32x4 __attribute__((ext_vector_type(4)));

union BF8 { u16x4 h[2]; unsigned short u[8]; bf16x8_t v; };
union U16X8 { u32x4 u; u16x4 h[2]; };

static __device__ __forceinline__ unsigned short f2bf(float f){
  union { float f; unsigned u; } x; x.f = f;
  unsigned r = x.u + 0x7FFFu + ((x.u >> 16) & 1u);
  return (unsigned short)(r >> 16);
}

// ---------------- fp32 -> bf16 (no transpose) ----------------
__global__ __launch_bounds__(256) void k_cvt(const float* __restrict__ in,
                                             unsigned short* __restrict__ out, int n4){
  int i = blockIdx.x*256 + threadIdx.x;
  int stride = gridDim.x*256;
  for (; i < n4; i += stride){
    f32x4_t v = ((const f32x4_t*)in)[i];
    u16x4 o; o.x=f2bf(v.x); o.y=f2bf(v.y); o.z=f2bf(v.z); o.w=f2bf(v.w);
    ((u16x4*)out)[i] = o;
  }
}

// ---------------- fp32 W[K][N] -> bf16 Wt[Npad][K] (transpose, zero pad rows >= N) --------
__global__ __launch_bounds__(256) void k_cvtT(const float* __restrict__ W,
                                              unsigned short* __restrict__ Wt, int K, int N){
  __shared__ float tile[32][33];
  int n0 = blockIdx.x*32, k0 = blockIdx.y*32;
  int r = threadIdx.x >> 3, c4 = (threadIdx.x & 7) * 4;
  f32x4_t v = {0.f,0.f,0.f,0.f};
  if (n0 + c4 < N) v = *(const f32x4_t*)(W + (size_t)(k0 + r)*N + n0 + c4);
  tile[r][c4+0]=v.x; tile[r][c4+1]=v.y; tile[r][c4+2]=v.z; tile[r][c4+3]=v.w;
  __syncthreads();
  u16x4 o;
  o.x = f2bf(tile[c4+0][r]); o.y = f2bf(tile[c4+1][r]);
  o.z = f2bf(tile[c4+2][r]); o.w = f2bf(tile[c4+3][r]);
  *(u16x4*)(Wt + (size_t)(n0 + r)*K + k0 + c4) = o;
}

// ---------------- GEMM: C[M][N] f32 = A[M][K] bf16 * Bt[N][K] bf16 ----------------
__global__ __launch_bounds__(256) void k_gemm(const unsigned short* __restrict__ A,
                                              const unsigned short* __restrict__ Bt,
                                              float* __restrict__ C, int M, int N, int K){
  __shared__ unsigned short sA[128][36];
  __shared__ unsigned short sB[128][36];
  int bn = blockIdx.x*128, bm = blockIdx.y*128;
  int tid = threadIdx.x;
  int w = tid >> 6, l = tid & 63, lr = l & 15, lg = l >> 4;
  int wm = (w >> 1)*64, wn = (w & 1)*64;
  f32x4_t acc[4][4];
  f32x4_t z4 = {0.f,0.f,0.f,0.f};
  #pragma unroll
  for (int i=0;i<4;i++)
    #pragma unroll
    for(int j=0;j<4;j++) acc[i][j] = z4;
  int r0 = tid >> 2, c8 = (tid & 3)*8;
  for (int k0 = 0; k0 < K; k0 += 32){
    #pragma unroll
    for (int it = 0; it < 2; ++it){
      int r = r0 + it*64;
      U16X8 ga, gb;
      ga.u = *(const u32x4*)(A  + (size_t)(bm + r)*K + k0 + c8);
      gb.u = *(const u32x4*)(Bt + (size_t)(bn + r)*K + k0 + c8);
      *(u16x4*)&sA[r][c8]   = ga.h[0];
      *(u16x4*)&sA[r][c8+4] = ga.h[1];
      *(u16x4*)&sB[r][c8]   = gb.h[0];
      *(u16x4*)&sB[r][c8+4] = gb.h[1];
    }
    __syncthreads();
    BF8 af[4], bfr[4];
    #pragma unroll
    for (int mf=0; mf<4; ++mf){
      af[mf].h[0]  = *(const u16x4*)&sA[wm + mf*16 + lr][4*lg];
      af[mf].h[1]  = *(const u16x4*)&sA[wm + mf*16 + lr][16 + 4*lg];
      bfr[mf].h[0] = *(const u16x4*)&sB[wn + mf*16 + lr][4*lg];
      bfr[mf].h[1] = *(const u16x4*)&sB[wn + mf*16 + lr][16 + 4*lg];
    }
    #pragma unroll
    for (int mf=0; mf<4; ++mf)
      #pragma unroll
      for (int nf=0; nf<4; ++nf)
        acc[mf][nf] = __builtin_amdgcn_mfma_f32_16x16x32_bf16(af[mf].v, bfr[nf].v, acc[mf][nf], 0,0,0);
    __syncthreads();
  }
  #pragma unroll
  for (int mf=0; mf<4; ++mf){
    int row = bm + wm + mf*16 + 4*lg;
    #pragma unroll
    for (int nf=0; nf<4; ++nf){
      int col = bn + wn + nf*16 + lr;
      #pragma unroll
      for (int rg=0; rg<4; ++rg)
        C[(size_t)(row + rg)*N + col] = acc[mf][nf][rg];
    }
  }
}

// ---------------- RMSNorm q_a -> q_c bf16 ----------------
__global__ __launch_bounds__(256) void k_rms_q(const float* __restrict__ qa,
                                               const float* __restrict__ w,
                                               unsigned short* __restrict__ qc){
  int t = blockIdx.x, tid = threadIdx.x;
  const float* row = qa + (size_t)t*Q_LORA;
  float ss = 0.f;
  for (int i = tid; i < Q_LORA; i += 256){ float x = row[i]; ss += x*x; }
  #pragma unroll
  for (int off=1; off<64; off<<=1) ss += __shfl_xor(ss, off, 64);
  __shared__ float red[4];
  if ((tid & 63) == 0) red[tid>>6] = ss;
  __syncthreads();
  ss = red[0]+red[1]+red[2]+red[3];
  float sc = rsqrtf(ss/(float)Q_LORA + 1e-6f);
  unsigned short* orow = qc + (size_t)t*Q_LORA;
  for (int i = tid; i < Q_LORA; i += 256) orow[i] = f2bf(row[i]*sc*w[i]);
}

// ------------- RMSNorm kv -> kv_c bf16 ; rope(k_pe) -> k_full[:, :, 128:192] all heads ----
__global__ __launch_bounds__(256) void k_rms_kv(const float* __restrict__ kvf,
                                                const float* __restrict__ w,
                                                const int* __restrict__ pos,
                                                unsigned short* __restrict__ kvc,
                                                unsigned short* __restrict__ k_full){
  int t = blockIdx.x, tid = threadIdx.x;
  const float* row = kvf + (size_t)t*KVA_NP;
  float ss = 0.f;
  for (int i = tid; i < KV_LORA; i += 256){ float x = row[i]; ss += x*x; }
  #pragma unroll
  for (int off=1; off<64; off<<=1) ss += __shfl_xor(ss, off, 64);
  __shared__ float red[4];
  if ((tid & 63) == 0) red[tid>>6] = ss;
  __syncthreads();
  ss = red[0]+red[1]+red[2]+red[3];
  float sc = rsqrtf(ss/(float)KV_LORA + 1e-6f);
  for (int i = tid; i < KV_LORA; i += 256)
    kvc[(size_t)t*KV_LORA + i] = f2bf(row[i]*sc*w[i]);
  if (tid < 32){
    int i = tid;
    float x1 = row[KV_LORA + 2*i], x2 = row[KV_LORA + 2*i + 1];
    float p = (float)pos[t];
    float invf = 1.0f / powf(10000.0f, (float)(2*i)/64.0f);
    float sn, cs; sincosf(p*invf, &sn, &cs);
    unsigned short b1 = f2bf(x1*cs - x2*sn), b2 = f2bf(x2*cs + x1*sn);
    for (int h=0; h<NH; ++h){
      unsigned short* kr = k_full + ((size_t)(h*T + t))*QK_HD + D_NOPE + 2*i;
      kr[0] = b1; kr[1] = b2;
    }
  }
}

// -------- scatter q: split nope / rope(pe), fold ATT_SCALE, -> q_full[h][t][192] bf16 -----
__global__ __launch_bounds__(256) void k_scat_q(const float* __restrict__ qf,
                                                const int* __restrict__ pos,
                                                unsigned short* __restrict__ q_full){
  int t = blockIdx.x, tid = threadIdx.x;
  const float* row = qf + (size_t)t*N_QB;
  for (int idx = tid; idx < NH*D_NOPE; idx += 256){
    int h = idx >> 7, d = idx & 127;
    q_full[((size_t)(h*T + t))*QK_HD + d] = f2bf(row[h*QK_HD + d] * ATT_SCALE);
  }
  float p = (float)pos[t];
  for (int idx = tid; idx < NH*32; idx += 256){
    int h = idx >> 5, i = idx & 31;
    float x1 = row[h*QK_HD + D_NOPE + 2*i], x2 = row[h*QK_HD + D_NOPE + 2*i+1];
    float invf = 1.0f / powf(10000.0f, (float)(2*i)/64.0f);
    float sn, cs; sincosf(p*invf, &sn, &cs);
    unsigned short* qr = q_full + ((size_t)(h*T + t))*QK_HD + D_NOPE + 2*i;
    qr[0] = f2bf((x1*cs - x2*sn)*ATT_SCALE);
    qr[1] = f2bf((x2*cs + x1*sn)*ATT_SCALE);
  }
}

// -------- scatter kv_up: k_nope -> k_full[h][t][0:128]; v -> vt[h][d][t] (transposed) -----
__global__ __launch_bounds__(256) void k_scat_kv(const float* __restrict__ kvup,
                                                 unsigned short* __restrict__ k_full,
                                                 unsigned short* __restrict__ vt){
  int h = blockIdx.y, t0 = blockIdx.x*32;
  int tid = threadIdx.x;
  __shared__ float vtile[32][129];
  #pragma unroll
  for (int it=0; it<16; ++it){
    int idx = tid + it*256;           // 4096 = 32 rows x 128 cols
    int r = idx >> 7, d = idx & 127;
    float kn = kvup[(size_t)(t0 + r)*N_KVB + h*256 + d];
    k_full[((size_t)(h*T + t0 + r))*QK_HD + d] = f2bf(kn);
    vtile[r][d] = kvup[(size_t)(t0 + r)*N_KVB + h*256 + 128 + d];
  }
  __syncthreads();
  int d = tid >> 1, half = tid & 1;
  unsigned short* vrow = vt + ((size_t)(h*128 + d))*T + t0 + half*16;
  #pragma unroll
  for (int c=0; c<4; ++c){
    u16x4 o;
    o.x = f2bf(vtile[half*16 + c*4 + 0][d]);
    o.y = f2bf(vtile[half*16 + c*4 + 1][d]);
    o.z = f2bf(vtile[half*16 + c*4 + 2][d]);
    o.w = f2bf(vtile[half*16 + c*4 + 3][d]);
    *(u16x4*)(vrow + c*4) = o;
  }
}

// ---------------- flash attention: 64 q-rows/block x 16 heads ----------------
__global__ __launch_bounds__(256) void k_attn(const unsigned short* __restrict__ q_full,
                                              const unsigned short* __restrict__ k_full,
                                              const unsigned short* __restrict__ vt,
                                              unsigned short* __restrict__ attn){
  __shared__ unsigned short K_lds[64][200];
  __shared__ unsigned short V_lds[128][72];
  __shared__ unsigned short P_lds[64][72];
  int qt = blockIdx.x, h = blockIdx.y;
  int tid = threadIdx.x, w = tid >> 6, l = tid & 63, lr = l & 15, lg = l >> 4;
  int qrow = qt*64 + w*16 + lr;
  BF8 qfrag[6];
  const unsigned short* qp = q_full + ((size_t)(h*T + qrow))*QK_HD;
  #pragma unroll
  for (int dk=0; dk<6; ++dk){
    qfrag[dk].h[0] = *(const u16x4*)(qp + dk*32 + 4*lg);
    qfrag[dk].h[1] = *(const u16x4*)(qp + dk*32 + 16 + 4*lg);
  }
  float m_run = -1e30f, l_run = 0.f;
  f32x4_t z4 = {0.f,0.f,0.f,0.f};
  f32x4_t o[8];
  #pragma unroll
  for (int i=0;i<8;i++) o[i] = z4;
  for (int st = 0; st <= qt; ++st){
    int s0 = st*64;
    #pragma unroll
    for (int it=0; it<6; ++it){
      int c = tid + it*256;           // 1536 chunks of 8 elems (64 x 192)
      int r = c / 24, cc = (c % 24)*8;
      u32x4 g = *(const u32x4*)(k_full + ((size_t)(h*T + s0 + r))*QK_HD + cc);
      *(u32x4*)&K_lds[r][cc] = g;
    }
    #pragma unroll
    for (int it=0; it<4; ++it){
      int c = tid + it*256;           // 1024 chunks (128 x 64)
      int d = c >> 3, cc = (c & 7)*8;
      u32x4 g = *(const u32x4*)(vt + ((size_t)(h*128 + d))*T + s0 + cc);
      *(u32x4*)&V_lds[d][cc] = g;
    }
    __syncthreads();
    f32x4_t sf[4];
    #pragma unroll
    for (int i=0;i<4;i++) sf[i] = z4;
    #pragma unroll
    for (int sfi=0; sfi<4; ++sfi){
      #pragma unroll
      for (int dk=0; dk<6; ++dk){
        BF8 a;
        a.h[0] = *(const u16x4*)&K_lds[sfi*16 + lr][dk*32 + 4*lg];
        a.h[1] = *(const u16x4*)&K_lds[sfi*16 + lr][dk*32 + 16 + 4*lg];
        sf[sfi] = __builtin_amdgcn_mfma_f32_16x16x32_bf16(a.v, qfrag[dk].v, sf[sfi], 0,0,0);
      }
    }
    float tmax = -1e30f;
    #pragma unroll
    for (int sfi=0; sfi<4; ++sfi){
      #pragma unroll
      for (int rg=0; rg<4; ++rg){
        int s_g = s0 + sfi*16 + 4*lg + rg;
        float v = sf[sfi][rg];
        if (st == qt && s_g > qrow) v = -1e30f;
        sf[sfi][rg] = v;
        tmax = fmaxf(tmax, v);
      }
    }
    tmax = fmaxf(tmax, __shfl_xor(tmax, 16, 64));
    tmax = fmaxf(tmax, __shfl_xor(tmax, 32, 64));
    float m_new = fmaxf(m_run, tmax);
    float alpha = __expf(m_run - m_new);
    float psum = 0.f;
    #pragma unroll
    for (int sfi=0; sfi<4; ++sfi){
      #pragma unroll
      for (int rg=0; rg<4; ++rg){
        float pv = __expf(sf[sfi][rg] - m_new);
        psum += pv;
        P_lds[sfi*16 + 4*lg + rg][w*16 + lr] = f2bf(pv);
      }
    }
    psum += __shfl_xor(psum, 16, 64);
    psum += __shfl_xor(psum, 32, 64);
    l_run = l_run*alpha + psum;
    m_run = m_new;
    #pragma unroll
    for (int i=0;i<8;i++){ o[i][0]*=alpha; o[i][1]*=alpha; o[i][2]*=alpha; o[i][3]*=alpha; }
    BF8 bp[2];
    #pragma unroll
    for (int ks=0; ks<2; ++ks)
      #pragma unroll
      for (int j=0; j<8; ++j)
        bp[ks].u[j] = P_lds[ks*32 + 16*(j>>2) + 4*lg + (j&3)][w*16 + lr];
    #pragma unroll
    for (int df=0; df<8; ++df){
      BF8 va0, va1;
      va0.h[0] = *(const u16x4*)&V_lds[df*16 + lr][4*lg];
      va0.h[1] = *(const u16x4*)&V_lds[df*16 + lr][16 + 4*lg];
      va1.h[0] = *(const u16x4*)&V_lds[df*16 + lr][32 + 4*lg];
      va1.h[1] = *(const u16x4*)&V_lds[df*16 + lr][48 + 4*lg];
      o[df] = __builtin_amdgcn_mfma_f32_16x16x32_bf16(va0.v, bp[0].v, o[df], 0,0,0);
      o[df] = __builtin_amdgcn_mfma_f32_16x16x32_bf16(va1.v, bp[1].v, o[df], 0,0,0);
    }
    __syncthreads();
  }
  float inv = 1.0f / l_run;
  #pragma unroll
  for (int df=0; df<8; ++df){
    u16x4 ov;
    ov.x = f2bf(o[df][0]*inv); ov.y = f2bf(o[df][1]*inv);
    ov.z = f2bf(o[df][2]*inv); ov.w = f2bf(o[df][3]*inv);
    *(u16x4*)(attn + (size_t)qrow*(NH*D_V) + h*D_V + df*16 + 4*lg) = ov;
  }
}

extern "C" void kernel_launch(void* const* d_in, const int* in_sizes, int n_in,
                              void* d_out, int out_size, void* d_ws, size_t ws_size,
                              hipStream_t stream){
  const int*   positions = (const int*)d_in[0];
  const float* hidden = (const float*)d_in[1];
  const float* w_qa   = (const float*)d_in[2];
  const float* qa_ln  = (const float*)d_in[3];
  const float* w_qb   = (const float*)d_in[4];
  const float* w_kva  = (const float*)d_in[5];
  const float* kva_ln = (const float*)d_in[6];
  const float* w_kvb  = (const float*)d_in[7];
  const float* w_o    = (const float*)d_in[8];
  float* out = (float*)d_out;

  char* p = (char*)d_ws;
  auto alloc = [&](size_t bytes){ void* r = (void*)p; p += (bytes + 255) & ~(size_t)255; return r; };
  unsigned short* hb     = (unsigned short*)alloc((size_t)T*HID*2);
  unsigned short* wqaT   = (unsigned short*)alloc((size_t)Q_LORA*HID*2);
  unsigned short* wqbT   = (unsigned short*)alloc((size_t)N_QB*Q_LORA*2);
  unsigned short* wkvaT  = (unsigned short*)alloc((size_t)KVA_NP*HID*2);
  unsigned short* wkvbT  = (unsigned short*)alloc((size_t)N_KVB*KV_LORA*2);
  unsigned short* woT    = (unsigned short*)alloc((size_t)HID*(NH*D_V)*2);
  float* q_a             = (float*)alloc((size_t)T*Q_LORA*4);
  unsigned short* q_c    = (unsigned short*)alloc((size_t)T*Q_LORA*2);
  float* qf              = (float*)alloc((size_t)T*N_QB*4);
  float* kvf             = (float*)alloc((size_t)T*KVA_NP*4);
  unsigned short* kv_c   = (unsigned short*)alloc((size_t)T*KV_LORA*2);
  float* kvupf           = (float*)alloc((size_t)T*N_KVB*4);
  unsigned short* q_full = (unsigned short*)alloc((size_t)NH*T*QK_HD*2);
  unsigned short* k_full = (unsigned short*)alloc((size_t)NH*T*QK_HD*2);
  unsigned short* vt     = (unsigned short*)alloc((size_t)NH*D_V*T*2);
  unsigned short* attnb  = (unsigned short*)alloc((size_t)T*NH*D_V*2);

  k_cvt<<<2048, 256, 0, stream>>>(hidden, hb, T*HID/4);
  k_cvtT<<<dim3(Q_LORA/32, HID/32), 256, 0, stream>>>(w_qa, wqaT, HID, Q_LORA);
  k_cvtT<<<dim3(N_QB/32, Q_LORA/32), 256, 0, stream>>>(w_qb, wqbT, Q_LORA, N_QB);
  k_cvtT<<<dim3(KVA_NP/32, HID/32), 256, 0, stream>>>(w_kva, wkvaT, HID, KVA_N);
  k_cvtT<<<dim3(N_KVB/32, KV_LORA/32), 256, 0, stream>>>(w_kvb, wkvbT, KV_LORA, N_KVB);
  k_cvtT<<<dim3(HID/32, (NH*D_V)/32), 256, 0, stream>>>(w_o, woT, NH*D_V, HID);

  k_gemm<<<dim3(Q_LORA/128, T/128), 256, 0, stream>>>(hb, wqaT, q_a, T, Q_LORA, HID);
  k_rms_q<<<T, 256, 0, stream>>>(q_a, qa_ln, q_c);
  k_gemm<<<dim3(N_QB/128, T/128), 256, 0, stream>>>(q_c, wqbT, qf, T, N_QB, Q_LORA);
  k_gemm<<<dim3(KVA_NP/128, T/128), 256, 0, stream>>>(hb, wkvaT, kvf, T, KVA_NP, HID);
  k_rms_kv<<<T, 256, 0, stream>>>(kvf, kva_ln, positions, kv_c, k_full);
  k_gemm<<<dim3(N_KVB/128, T/128), 256, 0, stream>>>(kv_c, wkvbT, kvupf, T, N_KVB, KV_LORA);
  k_scat_q<<<T, 256, 0, stream>>>(qf, positions, q_full);
  k_scat_kv<<<dim3(T/32, NH), 256, 0, stream>>>(kvupf, k_full, vt);
  k_attn<<<dim3(T/64, NH), 256, 0, stream>>>(q_full, k_full, vt, attnb);
  k_gemm<<<dim3(HID/128, T/128), 256, 0, stream>>>(attnb, woT, out, T, HID, NH*D_V);
}

// Round 3
// 770.071 us; speedup vs baseline: 1.0457x; 1.0457x over previous
//
#include <hip/hip_runtime.h>
#include <hip/hip_bf16.h>
#include <math.h>

#define T 2048
#define HID 5120
#define NH 16
#define D_NOPE 128
#define D_ROPE 64
#define D_V 128
#define Q_LORA 1536
#define KV_LORA 512
#define QK_HD 192
#define KVA_N 576
#define KVA_NP 640
#define N_QB (NH*QK_HD)          // 3072
#define N_KVB (NH*(D_NOPE+D_V))  // 4096
#define ATT_SCALE 0.07216878364870322f  // 192^-0.5

typedef __bf16 bf16x8_t __attribute__((ext_vector_type(8)));
typedef float f32x4_t __attribute__((ext_vector_type(4)));
typedef unsigned short u16x4 __attribute__((ext_vector_type(4)));
typedef unsigned int u32x4 __attribute__((ext_vector_type(4)));

union BF8 { u16x4 h[2]; unsigned short u[8]; bf16x8_t v; u32x4 q; };

static __device__ __forceinline__ unsigned short f2bf(float f){
  union { float f; unsigned u; } x; x.f = f;
  unsigned r = x.u + 0x7FFFu + ((x.u >> 16) & 1u);
  return (unsigned short)(r >> 16);
}

// async global->LDS, 16B per lane. LDS dest = wave-uniform base + lane*16.
static __device__ __forceinline__ void gload_lds16(const void* g, void* l){
  __builtin_amdgcn_global_load_lds(
      (const __attribute__((address_space(1))) void*)(unsigned long long)g,
      (__attribute__((address_space(3))) void*)(unsigned int)(unsigned long long)l,
      16, 0, 0);
}

// ---------------- fp32 -> bf16 (no transpose) ----------------
__global__ __launch_bounds__(256) void k_cvt(const float* __restrict__ in,
                                             unsigned short* __restrict__ out, int n4){
  int i = blockIdx.x*256 + threadIdx.x;
  int stride = gridDim.x*256;
  for (; i < n4; i += stride){
    f32x4_t v = ((const f32x4_t*)in)[i];
    u16x4 o; o.x=f2bf(v.x); o.y=f2bf(v.y); o.z=f2bf(v.z); o.w=f2bf(v.w);
    ((u16x4*)out)[i] = o;
  }
}

// ---------------- fp32 W[K][N] -> bf16 Wt[Npad][K] (transpose, zero pad rows >= N) --------
__global__ __launch_bounds__(256) void k_cvtT(const float* __restrict__ W,
                                              unsigned short* __restrict__ Wt, int K, int N){
  __shared__ float tile[32][33];
  int n0 = blockIdx.x*32, k0 = blockIdx.y*32;
  int r = threadIdx.x >> 3, c4 = (threadIdx.x & 7) * 4;
  f32x4_t v = {0.f,0.f,0.f,0.f};
  if (n0 + c4 < N) v = *(const f32x4_t*)(W + (size_t)(k0 + r)*N + n0 + c4);
  tile[r][c4+0]=v.x; tile[r][c4+1]=v.y; tile[r][c4+2]=v.z; tile[r][c4+3]=v.w;
  __syncthreads();
  u16x4 o;
  o.x = f2bf(tile[c4+0][r]); o.y = f2bf(tile[c4+1][r]);
  o.z = f2bf(tile[c4+2][r]); o.w = f2bf(tile[c4+3][r]);
  *(u16x4*)(Wt + (size_t)(n0 + r)*K + k0 + c4) = o;
}

// ---- GEMM (m97 structure): C[M][N] f32 = A[M][K] bf16 * Bt[N][K] bf16 ----
// linear LDS [128][32], global_load_lds width 16, ds_read_b128 fragments,
// contiguous-k fragment mapping (self-consistent for A and B).
__global__ __launch_bounds__(256) void k_gemm(const unsigned short* __restrict__ A,
                                              const unsigned short* __restrict__ Bt,
                                              float* __restrict__ C, int M, int N, int K){
  __shared__ unsigned short sA[128*32];
  __shared__ unsigned short sB[128*32];
  int bn = blockIdx.x*128, bm = blockIdx.y*128;
  int tid = threadIdx.x;
  int l = tid & 63, lr = l & 15, lg = l >> 4;
  int w = tid >> 6;
  int wm = (w >> 1)*64, wn = (w & 1)*64;
  f32x4_t acc[4][4];
  f32x4_t z4 = {0.f,0.f,0.f,0.f};
  #pragma unroll
  for (int i=0;i<4;i++)
    #pragma unroll
    for(int j=0;j<4;j++) acc[i][j] = z4;
  for (int k0 = 0; k0 < K; k0 += 32){
    __syncthreads();           // prev iter's LDS reads complete before overwrite
    #pragma unroll
    for (int it = 0; it < 2; ++it){
      int c = it*256 + tid;                // chunk 0..511, lane-ordered per wave
      int row = c >> 2, kc = (c & 3) * 8;
      gload_lds16(A  + (size_t)(bm + row)*K + k0 + kc, &sA[c*8]);
      gload_lds16(Bt + (size_t)(bn + row)*K + k0 + kc, &sB[c*8]);
    }
    __syncthreads();           // vmcnt(0) drain -> staged data visible
    BF8 af[4], bf[4];
    #pragma unroll
    for (int mf=0; mf<4; ++mf)
      af[mf].q = *(const u32x4*)&sA[(wm + mf*16 + lr)*32 + 8*lg];
    #pragma unroll
    for (int nf=0; nf<4; ++nf)
      bf[nf].q = *(const u32x4*)&sB[(wn + nf*16 + lr)*32 + 8*lg];
    #pragma unroll
    for (int mf=0; mf<4; ++mf)
      #pragma unroll
      for (int nf=0; nf<4; ++nf)
        acc[mf][nf] = __builtin_amdgcn_mfma_f32_16x16x32_bf16(af[mf].v, bf[nf].v, acc[mf][nf], 0,0,0);
  }
  #pragma unroll
  for (int mf=0; mf<4; ++mf){
    int row = bm + wm + mf*16 + 4*lg;
    #pragma unroll
    for (int nf=0; nf<4; ++nf){
      int col = bn + wn + nf*16 + lr;
      #pragma unroll
      for (int rg=0; rg<4; ++rg)
        C[(size_t)(row + rg)*N + col] = acc[mf][nf][rg];
    }
  }
}

// ---------------- RMSNorm q_a -> q_c bf16 ----------------
__global__ __launch_bounds__(256) void k_rms_q(const float* __restrict__ qa,
                                               const float* __restrict__ w,
                                               unsigned short* __restrict__ qc){
  int t = blockIdx.x, tid = threadIdx.x;
  const float* row = qa + (size_t)t*Q_LORA;
  float ss = 0.f;
  for (int i = tid; i < Q_LORA; i += 256){ float x = row[i]; ss += x*x; }
  #pragma unroll
  for (int off=1; off<64; off<<=1) ss += __shfl_xor(ss, off, 64);
  __shared__ float red[4];
  if ((tid & 63) == 0) red[tid>>6] = ss;
  __syncthreads();
  ss = red[0]+red[1]+red[2]+red[3];
  float sc = rsqrtf(ss/(float)Q_LORA + 1e-6f);
  unsigned short* orow = qc + (size_t)t*Q_LORA;
  for (int i = tid; i < Q_LORA; i += 256) orow[i] = f2bf(row[i]*sc*w[i]);
}

// ------------- RMSNorm kv -> kv_c bf16 ; rope(k_pe) -> k_full[:, :, 128:192] all heads ----
__global__ __launch_bounds__(256) void k_rms_kv(const float* __restrict__ kvf,
                                                const float* __restrict__ w,
                                                const int* __restrict__ pos,
                                                unsigned short* __restrict__ kvc,
                                                unsigned short* __restrict__ k_full){
  int t = blockIdx.x, tid = threadIdx.x;
  const float* row = kvf + (size_t)t*KVA_NP;
  float ss = 0.f;
  for (int i = tid; i < KV_LORA; i += 256){ float x = row[i]; ss += x*x; }
  #pragma unroll
  for (int off=1; off<64; off<<=1) ss += __shfl_xor(ss, off, 64);
  __shared__ float red[4];
  if ((tid & 63) == 0) red[tid>>6] = ss;
  __syncthreads();
  ss = red[0]+red[1]+red[2]+red[3];
  float sc = rsqrtf(ss/(float)KV_LORA + 1e-6f);
  for (int i = tid; i < KV_LORA; i += 256)
    kvc[(size_t)t*KV_LORA + i] = f2bf(row[i]*sc*w[i]);
  if (tid < 32){
    int i = tid;
    float x1 = row[KV_LORA + 2*i], x2 = row[KV_LORA + 2*i + 1];
    float p = (float)pos[t];
    float invf = 1.0f / powf(10000.0f, (float)(2*i)/64.0f);
    float sn, cs; sincosf(p*invf, &sn, &cs);
    unsigned short b1 = f2bf(x1*cs - x2*sn), b2 = f2bf(x2*cs + x1*sn);
    for (int h=0; h<NH; ++h){
      unsigned short* kr = k_full + ((size_t)(h*T + t))*QK_HD + D_NOPE + 2*i;
      kr[0] = b1; kr[1] = b2;
    }
  }
}

// -------- scatter q: split nope / rope(pe), fold ATT_SCALE, -> q_full[h][t][192] bf16 -----
__global__ __launch_bounds__(256) void k_scat_q(const float* __restrict__ qf,
                                                const int* __restrict__ pos,
                                                unsigned short* __restrict__ q_full){
  int t = blockIdx.x, tid = threadIdx.x;
  const float* row = qf + (size_t)t*N_QB;
  for (int idx = tid; idx < NH*D_NOPE; idx += 256){
    int h = idx >> 7, d = idx & 127;
    q_full[((size_t)(h*T + t))*QK_HD + d] = f2bf(row[h*QK_HD + d] * ATT_SCALE);
  }
  float p = (float)pos[t];
  for (int idx = tid; idx < NH*32; idx += 256){
    int h = idx >> 5, i = idx & 31;
    float x1 = row[h*QK_HD + D_NOPE + 2*i], x2 = row[h*QK_HD + D_NOPE + 2*i+1];
    float invf = 1.0f / powf(10000.0f, (float)(2*i)/64.0f);
    float sn, cs; sincosf(p*invf, &sn, &cs);
    unsigned short* qr = q_full + ((size_t)(h*T + t))*QK_HD + D_NOPE + 2*i;
    qr[0] = f2bf((x1*cs - x2*sn)*ATT_SCALE);
    qr[1] = f2bf((x2*cs + x1*sn)*ATT_SCALE);
  }
}

// -------- scatter kv_up: k_nope -> k_full[h][t][0:128]; v -> vt[h][d][t] (transposed) -----
__global__ __launch_bounds__(256) void k_scat_kv(const float* __restrict__ kvup,
                                                 unsigned short* __restrict__ k_full,
                                                 unsigned short* __restrict__ vt){
  int h = blockIdx.y, t0 = blockIdx.x*32;
  int tid = threadIdx.x;
  __shared__ float vtile[32][129];
  #pragma unroll
  for (int it=0; it<16; ++it){
    int idx = tid + it*256;           // 4096 = 32 rows x 128 cols
    int r = idx >> 7, d = idx & 127;
    float kn = kvup[(size_t)(t0 + r)*N_KVB + h*256 + d];
    k_full[((size_t)(h*T + t0 + r))*QK_HD + d] = f2bf(kn);
    vtile[r][d] = kvup[(size_t)(t0 + r)*N_KVB + h*256 + 128 + d];
  }
  __syncthreads();
  int d = tid >> 1, half = tid & 1;
  unsigned short* vrow = vt + ((size_t)(h*128 + d))*T + t0 + half*16;
  #pragma unroll
  for (int c=0; c<4; ++c){
    u16x4 o;
    o.x = f2bf(vtile[half*16 + c*4 + 0][d]);
    o.y = f2bf(vtile[half*16 + c*4 + 1][d]);
    o.z = f2bf(vtile[half*16 + c*4 + 2][d]);
    o.w = f2bf(vtile[half*16 + c*4 + 3][d]);
    *(u16x4*)(vrow + c*4) = o;
  }
}

// ------- flash attention: 1 wave per block, 16 q-rows, barrier-free, K/V from L2 -------
// grid 2048 blocks x 64 thr. XCD-aware head swizzle: XCD x serves heads {2x,2x+1}.
__global__ __launch_bounds__(64) void k_attn(const unsigned short* __restrict__ q_full,
                                             const unsigned short* __restrict__ k_full,
                                             const unsigned short* __restrict__ vt,
                                             unsigned short* __restrict__ attn){
  __shared__ unsigned short P_t[16][68];   // P transposed: [q][s], per-wave private
  int id = blockIdx.x;
  int h  = ((id & 7) << 1) | ((id >> 3) & 1);
  int qb = id >> 4;                        // 0..127, 16 q-rows each
  int l = threadIdx.x, lr = l & 15, lg = l >> 4;
  int qrow = qb*16 + lr;
  const unsigned short* qp = q_full + ((size_t)(h*T + qrow))*QK_HD;
  BF8 qfrag[6];
  #pragma unroll
  for (int dk=0; dk<6; ++dk)
    qfrag[dk].q = *(const u32x4*)(qp + dk*32 + 8*lg);
  float m_run = -1e30f, l_run = 0.f;
  f32x4_t z4 = {0.f,0.f,0.f,0.f};
  f32x4_t o[8];
  #pragma unroll
  for (int i=0;i<8;i++) o[i] = z4;
  int nst = (qb >> 2) + 1;
  for (int st = 0; st < nst; ++st){
    int s0 = st*64;
    f32x4_t sf[4];
    #pragma unroll
    for (int i=0;i<4;i++) sf[i] = z4;
    #pragma unroll
    for (int sfi=0; sfi<4; ++sfi){
      const unsigned short* kp = k_full + ((size_t)(h*T + s0 + sfi*16 + lr))*QK_HD + 8*lg;
      #pragma unroll
      for (int dk=0; dk<6; ++dk){
        BF8 a; a.q = *(const u32x4*)(kp + dk*32);
        sf[sfi] = __builtin_amdgcn_mfma_f32_16x16x32_bf16(a.v, qfrag[dk].v, sf[sfi], 0,0,0);
      }
    }
    bool lastt = (st == nst-1);
    float tmax = -1e30f;
    #pragma unroll
    for (int sfi=0; sfi<4; ++sfi){
      #pragma unroll
      for (int rg=0; rg<4; ++rg){
        int s_g = s0 + sfi*16 + 4*lg + rg;
        float v = sf[sfi][rg];
        if (lastt && s_g > qrow) v = -1e30f;
        sf[sfi][rg] = v;
        tmax = fmaxf(tmax, v);
      }
    }
    tmax = fmaxf(tmax, __shfl_xor(tmax, 16, 64));
    tmax = fmaxf(tmax, __shfl_xor(tmax, 32, 64));
    float m_new = fmaxf(m_run, tmax);
    float alpha = __expf(m_run - m_new);
    float psum = 0.f;
    #pragma unroll
    for (int sfi=0; sfi<4; ++sfi){
      #pragma unroll
      for (int rg=0; rg<4; ++rg){
        float pv = __expf(sf[sfi][rg] - m_new);
        psum += pv;
        P_t[lr][sfi*16 + 4*lg + rg] = f2bf(pv);   // [q][s]
      }
    }
    psum += __shfl_xor(psum, 16, 64);
    psum += __shfl_xor(psum, 32, 64);
    l_run = l_run*alpha + psum;
    m_run = m_new;
    #pragma unroll
    for (int i=0;i<8;i++){ o[i][0]*=alpha; o[i][1]*=alpha; o[i][2]*=alpha; o[i][3]*=alpha; }
    #pragma unroll
    for (int df=0; df<8; ++df){
      const unsigned short* vp = vt + ((size_t)(h*D_V + df*16 + lr))*T + s0 + 8*lg;
      #pragma unroll
      for (int ks=0; ks<2; ++ks){
        BF8 va; va.q = *(const u32x4*)(vp + ks*32);
        BF8 bp;
        bp.h[0] = *(const u16x4*)&P_t[lr][ks*32 + 8*lg];
        bp.h[1] = *(const u16x4*)&P_t[lr][ks*32 + 8*lg + 4];
        o[df] = __builtin_amdgcn_mfma_f32_16x16x32_bf16(va.v, bp.v, o[df], 0,0,0);
      }
    }
  }
  float inv = 1.0f / l_run;
  #pragma unroll
  for (int df=0; df<8; ++df){
    u16x4 ov;
    ov.x = f2bf(o[df][0]*inv); ov.y = f2bf(o[df][1]*inv);
    ov.z = f2bf(o[df][2]*inv); ov.w = f2bf(o[df][3]*inv);
    *(u16x4*)(attn + (size_t)qrow*(NH*D_V) + h*D_V + df*16 + 4*lg) = ov;
  }
}

extern "C" void kernel_launch(void* const* d_in, const int* in_sizes, int n_in,
                              void* d_out, int out_size, void* d_ws, size_t ws_size,
                              hipStream_t stream){
  const int*   positions = (const int*)d_in[0];
  const float* hidden = (const float*)d_in[1];
  const float* w_qa   = (const float*)d_in[2];
  const float* qa_ln  = (const float*)d_in[3];
  const float* w_qb   = (const float*)d_in[4];
  const float* w_kva  = (const float*)d_in[5];
  const float* kva_ln = (const float*)d_in[6];
  const float* w_kvb  = (const float*)d_in[7];
  const float* w_o    = (const float*)d_in[8];
  float* out = (float*)d_out;

  char* p = (char*)d_ws;
  auto alloc = [&](size_t bytes){ void* r = (void*)p; p += (bytes + 255) & ~(size_t)255; return r; };
  unsigned short* hb     = (unsigned short*)alloc((size_t)T*HID*2);
  unsigned short* wqaT   = (unsigned short*)alloc((size_t)Q_LORA*HID*2);
  unsigned short* wqbT   = (unsigned short*)alloc((size_t)N_QB*Q_LORA*2);
  unsigned short* wkvaT  = (unsigned short*)alloc((size_t)KVA_NP*HID*2);
  unsigned short* wkvbT  = (unsigned short*)alloc((size_t)N_KVB*KV_LORA*2);
  unsigned short* woT    = (unsigned short*)alloc((size_t)HID*(NH*D_V)*2);
  float* q_a             = (float*)alloc((size_t)T*Q_LORA*4);
  unsigned short* q_c    = (unsigned short*)alloc((size_t)T*Q_LORA*2);
  float* qf              = (float*)alloc((size_t)T*N_QB*4);
  float* kvf             = (float*)alloc((size_t)T*KVA_NP*4);
  unsigned short* kv_c   = (unsigned short*)alloc((size_t)T*KV_LORA*2);
  float* kvupf           = (float*)alloc((size_t)T*N_KVB*4);
  unsigned short* q_full = (unsigned short*)alloc((size_t)NH*T*QK_HD*2);
  unsigned short* k_full = (unsigned short*)alloc((size_t)NH*T*QK_HD*2);
  unsigned short* vt     = (unsigned short*)alloc((size_t)NH*D_V*T*2);
  unsigned short* attnb  = (unsigned short*)alloc((size_t)T*NH*D_V*2);

  k_cvt<<<2048, 256, 0, stream>>>(hidden, hb, T*HID/4);
  k_cvtT<<<dim3(Q_LORA/32, HID/32), 256, 0, stream>>>(w_qa, wqaT, HID, Q_LORA);
  k_cvtT<<<dim3(N_QB/32, Q_LORA/32), 256, 0, stream>>>(w_qb, wqbT, Q_LORA, N_QB);
  k_cvtT<<<dim3(KVA_NP/32, HID/32), 256, 0, stream>>>(w_kva, wkvaT, HID, KVA_N);
  k_cvtT<<<dim3(N_KVB/32, KV_LORA/32), 256, 0, stream>>>(w_kvb, wkvbT, KV_LORA, N_KVB);
  k_cvtT<<<dim3(HID/32, (NH*D_V)/32), 256, 0, stream>>>(w_o, woT, NH*D_V, HID);

  k_gemm<<<dim3(Q_LORA/128, T/128), 256, 0, stream>>>(hb, wqaT, q_a, T, Q_LORA, HID);
  k_rms_q<<<T, 256, 0, stream>>>(q_a, qa_ln, q_c);
  k_gemm<<<dim3(N_QB/128, T/128), 256, 0, stream>>>(q_c, wqbT, qf, T, N_QB, Q_LORA);
  k_gemm<<<dim3(KVA_NP/128, T/128), 256, 0, stream>>>(hb, wkvaT, kvf, T, KVA_NP, HID);
  k_rms_kv<<<T, 256, 0, stream>>>(kvf, kva_ln, positions, kv_c, k_full);
  k_gemm<<<dim3(N_KVB/128, T/128), 256, 0, stream>>>(kv_c, wkvbT, kvupf, T, N_KVB, KV_LORA);
  k_scat_q<<<T, 256, 0, stream>>>(qf, positions, q_full);
  k_scat_kv<<<dim3(T/32, NH), 256, 0, stream>>>(kvupf, k_full, vt);
  k_attn<<<2048, 64, 0, stream>>>(q_full, k_full, vt, attnb);
  k_gemm<<<dim3(HID/128, T/128), 256, 0, stream>>>(attnb, woT, out, T, HID, NH*D_V);
}

// Round 4
// 715.320 us; speedup vs baseline: 1.1258x; 1.0765x over previous
//
#include <hip/hip_runtime.h>
#include <hip/hip_bf16.h>
#include <math.h>

#define T 2048
#define HID 5120
#define NH 16
#define D_NOPE 128
#define D_ROPE 64
#define D_V 128
#define Q_LORA 1536
#define KV_LORA 512
#define QK_HD 192
#define KVA_N 576
#define KVA_NP 640
#define N_QB (NH*QK_HD)          // 3072
#define N_KVB (NH*(D_NOPE+D_V))  // 4096
#define ATT_SCALE 0.07216878364870322f  // 192^-0.5

typedef __bf16 bf16x8_t __attribute__((ext_vector_type(8)));
typedef float f32x4_t __attribute__((ext_vector_type(4)));
typedef unsigned short u16x4 __attribute__((ext_vector_type(4)));
typedef unsigned int u32x4 __attribute__((ext_vector_type(4)));

union BF8 { u16x4 h[2]; unsigned short u[8]; bf16x8_t v; u32x4 q; };

static __device__ __forceinline__ unsigned short f2bf(float f){
  union { float f; unsigned u; } x; x.f = f;
  unsigned r = x.u + 0x7FFFu + ((x.u >> 16) & 1u);
  return (unsigned short)(r >> 16);
}

// async global->LDS, 16B per lane. LDS dest = wave-uniform base + lane*16.
static __device__ __forceinline__ void gload_lds16(const void* g, void* l){
  __builtin_amdgcn_global_load_lds(
      (const __attribute__((address_space(1))) void*)(unsigned long long)g,
      (__attribute__((address_space(3))) void*)(unsigned int)(unsigned long long)l,
      16, 0, 0);
}

// ---------------- fp32 -> bf16 (no transpose) ----------------
__global__ __launch_bounds__(256) void k_cvt(const float* __restrict__ in,
                                             unsigned short* __restrict__ out, int n4){
  int i = blockIdx.x*256 + threadIdx.x;
  int stride = gridDim.x*256;
  for (; i < n4; i += stride){
    f32x4_t v = ((const f32x4_t*)in)[i];
    u16x4 o; o.x=f2bf(v.x); o.y=f2bf(v.y); o.z=f2bf(v.z); o.w=f2bf(v.w);
    ((u16x4*)out)[i] = o;
  }
}

// ---------------- fp32 W[K][N] -> bf16 Wt[Npad][K] (transpose, zero pad rows >= N) --------
__global__ __launch_bounds__(256) void k_cvtT(const float* __restrict__ W,
                                              unsigned short* __restrict__ Wt, int K, int N){
  __shared__ float tile[32][33];
  int n0 = blockIdx.x*32, k0 = blockIdx.y*32;
  int r = threadIdx.x >> 3, c4 = (threadIdx.x & 7) * 4;
  f32x4_t v = {0.f,0.f,0.f,0.f};
  if (n0 + c4 < N) v = *(const f32x4_t*)(W + (size_t)(k0 + r)*N + n0 + c4);
  tile[r][c4+0]=v.x; tile[r][c4+1]=v.y; tile[r][c4+2]=v.z; tile[r][c4+3]=v.w;
  __syncthreads();
  u16x4 o;
  o.x = f2bf(tile[c4+0][r]); o.y = f2bf(tile[c4+1][r]);
  o.z = f2bf(tile[c4+2][r]); o.w = f2bf(tile[c4+3][r]);
  *(u16x4*)(Wt + (size_t)(n0 + r)*K + k0 + c4) = o;
}

// ---- GEMM (m97 structure): C[M][N] f32 = A[M][K] bf16 * Bt[N][K] bf16 ----
__global__ __launch_bounds__(256) void k_gemm(const unsigned short* __restrict__ A,
                                              const unsigned short* __restrict__ Bt,
                                              float* __restrict__ C, int M, int N, int K){
  __shared__ unsigned short sA[128*32];
  __shared__ unsigned short sB[128*32];
  int bn = blockIdx.x*128, bm = blockIdx.y*128;
  int tid = threadIdx.x;
  int l = tid & 63, lr = l & 15, lg = l >> 4;
  int w = tid >> 6;
  int wm = (w >> 1)*64, wn = (w & 1)*64;
  f32x4_t acc[4][4];
  f32x4_t z4 = {0.f,0.f,0.f,0.f};
  #pragma unroll
  for (int i=0;i<4;i++)
    #pragma unroll
    for(int j=0;j<4;j++) acc[i][j] = z4;
  for (int k0 = 0; k0 < K; k0 += 32){
    __syncthreads();
    #pragma unroll
    for (int it = 0; it < 2; ++it){
      int c = it*256 + tid;
      int row = c >> 2, kc = (c & 3) * 8;
      gload_lds16(A  + (size_t)(bm + row)*K + k0 + kc, &sA[c*8]);
      gload_lds16(Bt + (size_t)(bn + row)*K + k0 + kc, &sB[c*8]);
    }
    __syncthreads();
    BF8 af[4], bf[4];
    #pragma unroll
    for (int mf=0; mf<4; ++mf)
      af[mf].q = *(const u32x4*)&sA[(wm + mf*16 + lr)*32 + 8*lg];
    #pragma unroll
    for (int nf=0; nf<4; ++nf)
      bf[nf].q = *(const u32x4*)&sB[(wn + nf*16 + lr)*32 + 8*lg];
    #pragma unroll
    for (int mf=0; mf<4; ++mf)
      #pragma unroll
      for (int nf=0; nf<4; ++nf)
        acc[mf][nf] = __builtin_amdgcn_mfma_f32_16x16x32_bf16(af[mf].v, bf[nf].v, acc[mf][nf], 0,0,0);
  }
  #pragma unroll
  for (int mf=0; mf<4; ++mf){
    int row = bm + wm + mf*16 + 4*lg;
    #pragma unroll
    for (int nf=0; nf<4; ++nf){
      int col = bn + wn + nf*16 + lr;
      #pragma unroll
      for (int rg=0; rg<4; ++rg)
        C[(size_t)(row + rg)*N + col] = acc[mf][nf][rg];
    }
  }
}

// ---------------- RMSNorm q_a -> q_c bf16 ----------------
__global__ __launch_bounds__(256) void k_rms_q(const float* __restrict__ qa,
                                               const float* __restrict__ w,
                                               unsigned short* __restrict__ qc){
  int t = blockIdx.x, tid = threadIdx.x;
  const float* row = qa + (size_t)t*Q_LORA;
  float ss = 0.f;
  for (int i = tid; i < Q_LORA; i += 256){ float x = row[i]; ss += x*x; }
  #pragma unroll
  for (int off=1; off<64; off<<=1) ss += __shfl_xor(ss, off, 64);
  __shared__ float red[4];
  if ((tid & 63) == 0) red[tid>>6] = ss;
  __syncthreads();
  ss = red[0]+red[1]+red[2]+red[3];
  float sc = rsqrtf(ss/(float)Q_LORA + 1e-6f);
  unsigned short* orow = qc + (size_t)t*Q_LORA;
  for (int i = tid; i < Q_LORA; i += 256) orow[i] = f2bf(row[i]*sc*w[i]);
}

// ------------- RMSNorm kv -> kv_c bf16 ; rope(k_pe) -> k_full[:, :, 128:192] all heads ----
__global__ __launch_bounds__(256) void k_rms_kv(const float* __restrict__ kvf,
                                                const float* __restrict__ w,
                                                const int* __restrict__ pos,
                                                unsigned short* __restrict__ kvc,
                                                unsigned short* __restrict__ k_full){
  int t = blockIdx.x, tid = threadIdx.x;
  const float* row = kvf + (size_t)t*KVA_NP;
  float ss = 0.f;
  for (int i = tid; i < KV_LORA; i += 256){ float x = row[i]; ss += x*x; }
  #pragma unroll
  for (int off=1; off<64; off<<=1) ss += __shfl_xor(ss, off, 64);
  __shared__ float red[4];
  if ((tid & 63) == 0) red[tid>>6] = ss;
  __syncthreads();
  ss = red[0]+red[1]+red[2]+red[3];
  float sc = rsqrtf(ss/(float)KV_LORA + 1e-6f);
  for (int i = tid; i < KV_LORA; i += 256)
    kvc[(size_t)t*KV_LORA + i] = f2bf(row[i]*sc*w[i]);
  if (tid < 32){
    int i = tid;
    float x1 = row[KV_LORA + 2*i], x2 = row[KV_LORA + 2*i + 1];
    float p = (float)pos[t];
    float invf = 1.0f / powf(10000.0f, (float)(2*i)/64.0f);
    float sn, cs; sincosf(p*invf, &sn, &cs);
    unsigned short b1 = f2bf(x1*cs - x2*sn), b2 = f2bf(x2*cs + x1*sn);
    for (int h=0; h<NH; ++h){
      unsigned short* kr = k_full + ((size_t)(h*T + t))*QK_HD + D_NOPE + 2*i;
      kr[0] = b1; kr[1] = b2;
    }
  }
}

// -------- scatter q: split nope / rope(pe), fold ATT_SCALE, -> q_full[h][t][192] bf16 -----
__global__ __launch_bounds__(256) void k_scat_q(const float* __restrict__ qf,
                                                const int* __restrict__ pos,
                                                unsigned short* __restrict__ q_full){
  int t = blockIdx.x, tid = threadIdx.x;
  const float* row = qf + (size_t)t*N_QB;
  for (int idx = tid; idx < NH*D_NOPE; idx += 256){
    int h = idx >> 7, d = idx & 127;
    q_full[((size_t)(h*T + t))*QK_HD + d] = f2bf(row[h*QK_HD + d] * ATT_SCALE);
  }
  float p = (float)pos[t];
  for (int idx = tid; idx < NH*32; idx += 256){
    int h = idx >> 5, i = idx & 31;
    float x1 = row[h*QK_HD + D_NOPE + 2*i], x2 = row[h*QK_HD + D_NOPE + 2*i+1];
    float invf = 1.0f / powf(10000.0f, (float)(2*i)/64.0f);
    float sn, cs; sincosf(p*invf, &sn, &cs);
    unsigned short* qr = q_full + ((size_t)(h*T + t))*QK_HD + D_NOPE + 2*i;
    qr[0] = f2bf((x1*cs - x2*sn)*ATT_SCALE);
    qr[1] = f2bf((x2*cs + x1*sn)*ATT_SCALE);
  }
}

// -------- scatter kv_up: k_nope -> k_full[h][t][0:128]; v -> vt[h][d][t] (transposed) -----
__global__ __launch_bounds__(256) void k_scat_kv(const float* __restrict__ kvup,
                                                 unsigned short* __restrict__ k_full,
                                                 unsigned short* __restrict__ vt){
  int h = blockIdx.y, t0 = blockIdx.x*32;
  int tid = threadIdx.x;
  __shared__ float vtile[32][129];
  #pragma unroll
  for (int it=0; it<16; ++it){
    int idx = tid + it*256;
    int r = idx >> 7, d = idx & 127;
    float kn = kvup[(size_t)(t0 + r)*N_KVB + h*256 + d];
    k_full[((size_t)(h*T + t0 + r))*QK_HD + d] = f2bf(kn);
    vtile[r][d] = kvup[(size_t)(t0 + r)*N_KVB + h*256 + 128 + d];
  }
  __syncthreads();
  int d = tid >> 1, half = tid & 1;
  unsigned short* vrow = vt + ((size_t)(h*128 + d))*T + t0 + half*16;
  #pragma unroll
  for (int c=0; c<4; ++c){
    u16x4 o;
    o.x = f2bf(vtile[half*16 + c*4 + 0][d]);
    o.y = f2bf(vtile[half*16 + c*4 + 1][d]);
    o.z = f2bf(vtile[half*16 + c*4 + 2][d]);
    o.w = f2bf(vtile[half*16 + c*4 + 3][d]);
    *(u16x4*)(vrow + c*4) = o;
  }
}

// ------- flash attention, paired-causal, 4 waves, K-dbuf LDS + V reg-prefetch -------
// 256 blocks x 256 thr. Block = head x pair (qtA=qp, qtB=31-qp): 33 tile-computes
// per block (constant). Wave w owns rows [qtA*64+w*16, +16) and [qtB*64+w*16, +16).
// K tile [64s][192d] staged swizzled: chunk3=d/64, slot=(d%64)/8;
// phys slot = slot ^ (row&7) applied on BOTH global source and ds_read.
__global__ __launch_bounds__(256,1) void k_attn(const unsigned short* __restrict__ q_full,
                                                const unsigned short* __restrict__ k_full,
                                                const unsigned short* __restrict__ vt,
                                                unsigned short* __restrict__ attn){
  __shared__ unsigned short K_lds[2][3*64*8*8];   // 2 x 24 KB
  __shared__ unsigned short P_t[4][16][68];
  int bid = blockIdx.x;
  int h  = ((bid & 7) << 1) | ((bid >> 3) & 1);   // 2 heads per XCD
  int qp = bid >> 4;                              // 0..15
  int qtA = qp, qtB = 31 - qp;
  int ntiles = qtB + 1;                           // 17..32
  int tid = threadIdx.x, w = tid >> 6, l = tid & 63, lr = l & 15, lg = l >> 4;
  int qrowA = qtA*64 + w*16 + lr;
  int qrowB = qtB*64 + w*16 + lr;
  BF8 qfA[6], qfB[6];
  {
    const unsigned short* qa = q_full + ((size_t)(h*T + qrowA))*QK_HD + 8*lg;
    const unsigned short* qb = q_full + ((size_t)(h*T + qrowB))*QK_HD + 8*lg;
    #pragma unroll
    for (int dk=0; dk<6; ++dk){
      qfA[dk].q = *(const u32x4*)(qa + dk*32);
      qfB[dk].q = *(const u32x4*)(qb + dk*32);
    }
  }
  float mA = -1e30f, lA = 0.f, mB = -1e30f, lB = 0.f;
  f32x4_t z4 = {0.f,0.f,0.f,0.f};
  f32x4_t oA[8], oB[8];
  #pragma unroll
  for (int i=0;i<8;i++){ oA[i] = z4; oB[i] = z4; }

  const unsigned short* kbase = k_full + (size_t)h*T*QK_HD;
  // stage K tile t into buf b: 1536 chunks of 16B, pre-swizzled source
  auto stageK = [&](int b, int t){
    #pragma unroll
    for (int is=0; is<6; ++is){
      int c = is*256 + tid;
      int chunk3 = c >> 9, row = (c >> 3) & 63, slot = c & 7;
      gload_lds16(kbase + (size_t)(t*64 + row)*QK_HD + chunk3*64 + ((slot ^ (row & 7))*8),
                  &K_lds[b][c*8]);
    }
  };
  stageK(0, 0);
  __syncthreads();
  int p = 0;
  int pslot0 = lg ^ (lr & 7), pslot1 = (4 + lg) ^ (lr & 7);   // swizzled read slots
  for (int t = 0; t < ntiles; ++t){
    int s0 = t*64;
    // ---- V register prefetch (T14): 16 b128 loads, hidden under QK^T+softmax ----
    BF8 va[8][2];
    #pragma unroll
    for (int df=0; df<8; ++df){
      const unsigned short* vp = vt + ((size_t)(h*D_V + df*16 + lr))*T + s0 + 8*lg;
      va[df][0].q = *(const u32x4*)(vp);
      va[df][1].q = *(const u32x4*)(vp + 32);
    }
    if (t+1 < ntiles) stageK(p^1, t+1);
    bool actA = (t <= qtA);
    // ---- QK^T: shared K fragment feeds both groups ----
    f32x4_t sA[4], sB[4];
    #pragma unroll
    for (int i=0;i<4;i++){ sA[i] = z4; sB[i] = z4; }
    #pragma unroll
    for (int sfi=0; sfi<4; ++sfi){
      int rbase = (sfi*16 + lr)*8;
      #pragma unroll
      for (int dk=0; dk<6; ++dk){
        int ps = (dk & 1) ? pslot1 : pslot0;
        BF8 a; a.q = *(const u32x4*)&K_lds[p][(((dk>>1)*64*8) + rbase + ps)*8];
        sB[sfi] = __builtin_amdgcn_mfma_f32_16x16x32_bf16(a.v, qfB[dk].v, sB[sfi], 0,0,0);
        if (actA)
          sA[sfi] = __builtin_amdgcn_mfma_f32_16x16x32_bf16(a.v, qfA[dk].v, sA[sfi], 0,0,0);
      }
    }
    // ---- group B softmax + PV (B active every tile) ----
    {
      bool diag = (t == ntiles-1);
      float tmax = -1e30f;
      #pragma unroll
      for (int sfi=0; sfi<4; ++sfi){
        #pragma unroll
        for (int rg=0; rg<4; ++rg){
          int s_g = s0 + sfi*16 + 4*lg + rg;
          float v = sB[sfi][rg];
          if (diag && s_g > qrowB) v = -1e30f;
          sB[sfi][rg] = v;
          tmax = fmaxf(tmax, v);
        }
      }
      tmax = fmaxf(tmax, __shfl_xor(tmax, 16, 64));
      tmax = fmaxf(tmax, __shfl_xor(tmax, 32, 64));
      float m_new = fmaxf(mB, tmax);
      float alpha = __expf(mB - m_new);
      float psum = 0.f;
      #pragma unroll
      for (int sfi=0; sfi<4; ++sfi){
        #pragma unroll
        for (int rg=0; rg<4; ++rg){
          float pv = __expf(sB[sfi][rg] - m_new);
          psum += pv;
          P_t[w][lr][sfi*16 + 4*lg + rg] = f2bf(pv);
        }
      }
      psum += __shfl_xor(psum, 16, 64);
      psum += __shfl_xor(psum, 32, 64);
      lB = lB*alpha + psum;
      mB = m_new;
      BF8 bp[2];
      #pragma unroll
      for (int ks=0; ks<2; ++ks){
        bp[ks].h[0] = *(const u16x4*)&P_t[w][lr][ks*32 + 8*lg];
        bp[ks].h[1] = *(const u16x4*)&P_t[w][lr][ks*32 + 8*lg + 4];
      }
      #pragma unroll
      for (int df=0; df<8; ++df){
        oB[df][0]*=alpha; oB[df][1]*=alpha; oB[df][2]*=alpha; oB[df][3]*=alpha;
        oB[df] = __builtin_amdgcn_mfma_f32_16x16x32_bf16(va[df][0].v, bp[0].v, oB[df], 0,0,0);
        oB[df] = __builtin_amdgcn_mfma_f32_16x16x32_bf16(va[df][1].v, bp[1].v, oB[df], 0,0,0);
      }
    }
    // ---- group A softmax + PV (first qtA+1 tiles) ----
    if (actA){
      bool diag = (t == qtA);
      float tmax = -1e30f;
      #pragma unroll
      for (int sfi=0; sfi<4; ++sfi){
        #pragma unroll
        for (int rg=0; rg<4; ++rg){
          int s_g = s0 + sfi*16 + 4*lg + rg;
          float v = sA[sfi][rg];
          if (diag && s_g > qrowA) v = -1e30f;
          sA[sfi][rg] = v;
          tmax = fmaxf(tmax, v);
        }
      }
      tmax = fmaxf(tmax, __shfl_xor(tmax, 16, 64));
      tmax = fmaxf(tmax, __shfl_xor(tmax, 32, 64));
      float m_new = fmaxf(mA, tmax);
      float alpha = __expf(mA - m_new);
      float psum = 0.f;
      #pragma unroll
      for (int sfi=0; sfi<4; ++sfi){
        #pragma unroll
        for (int rg=0; rg<4; ++rg){
          float pv = __expf(sA[sfi][rg] - m_new);
          psum += pv;
          P_t[w][lr][sfi*16 + 4*lg + rg] = f2bf(pv);
        }
      }
      psum += __shfl_xor(psum, 16, 64);
      psum += __shfl_xor(psum, 32, 64);
      lA = lA*alpha + psum;
      mA = m_new;
      BF8 bp[2];
      #pragma unroll
      for (int ks=0; ks<2; ++ks){
        bp[ks].h[0] = *(const u16x4*)&P_t[w][lr][ks*32 + 8*lg];
        bp[ks].h[1] = *(const u16x4*)&P_t[w][lr][ks*32 + 8*lg + 4];
      }
      #pragma unroll
      for (int df=0; df<8; ++df){
        oA[df][0]*=alpha; oA[df][1]*=alpha; oA[df][2]*=alpha; oA[df][3]*=alpha;
        oA[df] = __builtin_amdgcn_mfma_f32_16x16x32_bf16(va[df][0].v, bp[0].v, oA[df], 0,0,0);
        oA[df] = __builtin_amdgcn_mfma_f32_16x16x32_bf16(va[df][1].v, bp[1].v, oA[df], 0,0,0);
      }
    }
    __syncthreads();
    p ^= 1;
  }
  float invA = 1.0f / lA, invB = 1.0f / lB;
  #pragma unroll
  for (int df=0; df<8; ++df){
    u16x4 ov;
    ov.x = f2bf(oA[df][0]*invA); ov.y = f2bf(oA[df][1]*invA);
    ov.z = f2bf(oA[df][2]*invA); ov.w = f2bf(oA[df][3]*invA);
    *(u16x4*)(attn + (size_t)qrowA*(NH*D_V) + h*D_V + df*16 + 4*lg) = ov;
    ov.x = f2bf(oB[df][0]*invB); ov.y = f2bf(oB[df][1]*invB);
    ov.z = f2bf(oB[df][2]*invB); ov.w = f2bf(oB[df][3]*invB);
    *(u16x4*)(attn + (size_t)qrowB*(NH*D_V) + h*D_V + df*16 + 4*lg) = ov;
  }
}

extern "C" void kernel_launch(void* const* d_in, const int* in_sizes, int n_in,
                              void* d_out, int out_size, void* d_ws, size_t ws_size,
                              hipStream_t stream){
  const int*   positions = (const int*)d_in[0];
  const float* hidden = (const float*)d_in[1];
  const float* w_qa   = (const float*)d_in[2];
  const float* qa_ln  = (const float*)d_in[3];
  const float* w_qb   = (const float*)d_in[4];
  const float* w_kva  = (const float*)d_in[5];
  const float* kva_ln = (const float*)d_in[6];
  const float* w_kvb  = (const float*)d_in[7];
  const float* w_o    = (const float*)d_in[8];
  float* out = (float*)d_out;

  char* p = (char*)d_ws;
  auto alloc = [&](size_t bytes){ void* r = (void*)p; p += (bytes + 255) & ~(size_t)255; return r; };
  unsigned short* hb     = (unsigned short*)alloc((size_t)T*HID*2);
  unsigned short* wqaT   = (unsigned short*)alloc((size_t)Q_LORA*HID*2);
  unsigned short* wqbT   = (unsigned short*)alloc((size_t)N_QB*Q_LORA*2);
  unsigned short* wkvaT  = (unsigned short*)alloc((size_t)KVA_NP*HID*2);
  unsigned short* wkvbT  = (unsigned short*)alloc((size_t)N_KVB*KV_LORA*2);
  unsigned short* woT    = (unsigned short*)alloc((size_t)HID*(NH*D_V)*2);
  float* q_a             = (float*)alloc((size_t)T*Q_LORA*4);
  unsigned short* q_c    = (unsigned short*)alloc((size_t)T*Q_LORA*2);
  float* qf              = (float*)alloc((size_t)T*N_QB*4);
  float* kvf             = (float*)alloc((size_t)T*KVA_NP*4);
  unsigned short* kv_c   = (unsigned short*)alloc((size_t)T*KV_LORA*2);
  float* kvupf           = (float*)alloc((size_t)T*N_KVB*4);
  unsigned short* q_full = (unsigned short*)alloc((size_t)NH*T*QK_HD*2);
  unsigned short* k_full = (unsigned short*)alloc((size_t)NH*T*QK_HD*2);
  unsigned short* vt     = (unsigned short*)alloc((size_t)NH*D_V*T*2);
  unsigned short* attnb  = (unsigned short*)alloc((size_t)T*NH*D_V*2);

  k_cvt<<<2048, 256, 0, stream>>>(hidden, hb, T*HID/4);
  k_cvtT<<<dim3(Q_LORA/32, HID/32), 256, 0, stream>>>(w_qa, wqaT, HID, Q_LORA);
  k_cvtT<<<dim3(N_QB/32, Q_LORA/32), 256, 0, stream>>>(w_qb, wqbT, Q_LORA, N_QB);
  k_cvtT<<<dim3(KVA_NP/32, HID/32), 256, 0, stream>>>(w_kva, wkvaT, HID, KVA_N);
  k_cvtT<<<dim3(N_KVB/32, KV_LORA/32), 256, 0, stream>>>(w_kvb, wkvbT, KV_LORA, N_KVB);
  k_cvtT<<<dim3(HID/32, (NH*D_V)/32), 256, 0, stream>>>(w_o, woT, NH*D_V, HID);

  k_gemm<<<dim3(Q_LORA/128, T/128), 256, 0, stream>>>(hb, wqaT, q_a, T, Q_LORA, HID);
  k_rms_q<<<T, 256, 0, stream>>>(q_a, qa_ln, q_c);
  k_gemm<<<dim3(N_QB/128, T/128), 256, 0, stream>>>(q_c, wqbT, qf, T, N_QB, Q_LORA);
  k_gemm<<<dim3(KVA_NP/128, T/128), 256, 0, stream>>>(hb, wkvaT, kvf, T, KVA_NP, HID);
  k_rms_kv<<<T, 256, 0, stream>>>(kvf, kva_ln, positions, kv_c, k_full);
  k_gemm<<<dim3(N_KVB/128, T/128), 256, 0, stream>>>(kv_c, wkvbT, kvupf, T, N_KVB, KV_LORA);
  k_scat_q<<<T, 256, 0, stream>>>(qf, positions, q_full);
  k_scat_kv<<<dim3(T/32, NH), 256, 0, stream>>>(kvupf, k_full, vt);
  k_attn<<<256, 256, 0, stream>>>(q_full, k_full, vt, attnb);
  k_gemm<<<dim3(HID/128, T/128), 256, 0, stream>>>(attnb, woT, out, T, HID, NH*D_V);
}

// Round 5
// 582.527 us; speedup vs baseline: 1.3824x; 1.2280x over previous
//
#include <hip/hip_runtime.h>
#include <hip/hip_bf16.h>
#include <math.h>

#define T 2048
#define HID 5120
#define NH 16
#define D_NOPE 128
#define D_ROPE 64
#define D_V 128
#define Q_LORA 1536
#define KV_LORA 512
#define QK_HD 192
#define KVA_N 576
#define KVA_NP 640
#define N_QKVA (Q_LORA + KVA_NP)  // 2176
#define N_QB (NH*QK_HD)          // 3072
#define N_KVB (NH*(D_NOPE+D_V))  // 4096
#define ATT_SCALE 0.07216878364870322f  // 192^-0.5

typedef __bf16 bf16x8_t __attribute__((ext_vector_type(8)));
typedef float f32x4_t __attribute__((ext_vector_type(4)));
typedef unsigned short u16x4 __attribute__((ext_vector_type(4)));
typedef unsigned int u32x4 __attribute__((ext_vector_type(4)));

union BF8 { u16x4 h[2]; unsigned short u[8]; bf16x8_t v; u32x4 q; };

static __device__ __forceinline__ unsigned short f2bf(float f){
  union { float f; unsigned u; } x; x.f = f;
  unsigned r = x.u + 0x7FFFu + ((x.u >> 16) & 1u);
  return (unsigned short)(r >> 16);
}

// async global->LDS, 16B per lane. LDS dest = wave-uniform base + lane*16.
static __device__ __forceinline__ void gload_lds16(const void* g, void* l){
  __builtin_amdgcn_global_load_lds(
      (const __attribute__((address_space(1))) void*)(unsigned long long)g,
      (__attribute__((address_space(3))) void*)(unsigned int)(unsigned long long)l,
      16, 0, 0);
}

// ---------------- fp32 -> bf16 (no transpose) ----------------
__global__ __launch_bounds__(256) void k_cvt(const float* __restrict__ in,
                                             unsigned short* __restrict__ out, int n4){
  int i = blockIdx.x*256 + threadIdx.x;
  int stride = gridDim.x*256;
  for (; i < n4; i += stride){
    f32x4_t v = ((const f32x4_t*)in)[i];
    u16x4 o; o.x=f2bf(v.x); o.y=f2bf(v.y); o.z=f2bf(v.z); o.w=f2bf(v.w);
    ((u16x4*)out)[i] = o;
  }
}

// ---------------- fp32 W[K][N] -> bf16 Wt[Npad][K] (transpose, zero pad rows >= N) --------
__global__ __launch_bounds__(256) void k_cvtT(const float* __restrict__ W,
                                              unsigned short* __restrict__ Wt, int K, int N){
  __shared__ float tile[32][33];
  int n0 = blockIdx.x*32, k0 = blockIdx.y*32;
  int r = threadIdx.x >> 3, c4 = (threadIdx.x & 7) * 4;
  f32x4_t v = {0.f,0.f,0.f,0.f};
  if (n0 + c4 < N) v = *(const f32x4_t*)(W + (size_t)(k0 + r)*N + n0 + c4);
  tile[r][c4+0]=v.x; tile[r][c4+1]=v.y; tile[r][c4+2]=v.z; tile[r][c4+3]=v.w;
  __syncthreads();
  u16x4 o;
  o.x = f2bf(tile[c4+0][r]); o.y = f2bf(tile[c4+1][r]);
  o.z = f2bf(tile[c4+2][r]); o.w = f2bf(tile[c4+3][r]);
  *(u16x4*)(Wt + (size_t)(n0 + r)*K + k0 + c4) = o;
}

// ---- GEMM (m97 structure + split-K + XCD swizzle) ----
// C[s][M][N] partial = A[M][kBeg:kEnd] * Bt[N][kBeg:kEnd], s = blockIdx.z.
// grid (N/128, M/128, S); requires (gridDim.x*gridDim.y) % 8 == 0 for swizzle.
__global__ __launch_bounds__(256) void k_gemm(const unsigned short* __restrict__ A,
                                              const unsigned short* __restrict__ Bt,
                                              float* __restrict__ C,
                                              int M, int N, int K, int kChunk){
  __shared__ unsigned short sA[128*32];
  __shared__ unsigned short sB[128*32];
  int gx = gridDim.x;
  int nwg = gx*gridDim.y;
  int id = blockIdx.x + gx*blockIdx.y;
  int cpx = nwg >> 3;
  int swz = (id & 7)*cpx + (id >> 3);     // bijective when nwg%8==0
  int bn = (swz % gx)*128, bm = (swz / gx)*128;
  int kBeg = blockIdx.z*kChunk;
  int kEnd = kBeg + kChunk; if (kEnd > K) kEnd = K;
  float* Cs = C + (size_t)blockIdx.z*M*N;
  int tid = threadIdx.x;
  int l = tid & 63, lr = l & 15, lg = l >> 4;
  int w = tid >> 6;
  int wm = (w >> 1)*64, wn = (w & 1)*64;
  f32x4_t acc[4][4];
  f32x4_t z4 = {0.f,0.f,0.f,0.f};
  #pragma unroll
  for (int i=0;i<4;i++)
    #pragma unroll
    for(int j=0;j<4;j++) acc[i][j] = z4;
  for (int k0 = kBeg; k0 < kEnd; k0 += 32){
    __syncthreads();
    #pragma unroll
    for (int it = 0; it < 2; ++it){
      int c = it*256 + tid;
      int row = c >> 2, kc = (c & 3) * 8;
      gload_lds16(A  + (size_t)(bm + row)*K + k0 + kc, &sA[c*8]);
      gload_lds16(Bt + (size_t)(bn + row)*K + k0 + kc, &sB[c*8]);
    }
    __syncthreads();
    BF8 af[4], bf[4];
    #pragma unroll
    for (int mf=0; mf<4; ++mf)
      af[mf].q = *(const u32x4*)&sA[(wm + mf*16 + lr)*32 + 8*lg];
    #pragma unroll
    for (int nf=0; nf<4; ++nf)
      bf[nf].q = *(const u32x4*)&sB[(wn + nf*16 + lr)*32 + 8*lg];
    #pragma unroll
    for (int mf=0; mf<4; ++mf)
      #pragma unroll
      for (int nf=0; nf<4; ++nf)
        acc[mf][nf] = __builtin_amdgcn_mfma_f32_16x16x32_bf16(af[mf].v, bf[nf].v, acc[mf][nf], 0,0,0);
  }
  #pragma unroll
  for (int mf=0; mf<4; ++mf){
    int row = bm + wm + mf*16 + 4*lg;
    #pragma unroll
    for (int nf=0; nf<4; ++nf){
      int col = bn + wn + nf*16 + lr;
      #pragma unroll
      for (int rg=0; rg<4; ++rg)
        Cs[(size_t)(row + rg)*N + col] = acc[mf][nf][rg];
    }
  }
}

// ---------------- reduce 3 split-K slices of [T][2176] -> qkva fp32 ----------------
__global__ __launch_bounds__(256) void k_red3(const float* __restrict__ P,
                                              float* __restrict__ out, int n4){
  const size_t sstr = (size_t)T*N_QKVA/4;
  int i = blockIdx.x*256 + threadIdx.x, stride = gridDim.x*256;
  const f32x4_t* p4 = (const f32x4_t*)P;
  f32x4_t* o4 = (f32x4_t*)out;
  for (; i < n4; i += stride)
    o4[i] = p4[i] + p4[i+sstr] + p4[i+2*sstr];
}

// ------- reduce 2 split-K slices of QB output + scale/rope -> q_full bf16 [h][t][192] ----
__global__ __launch_bounds__(256) void k_red_q(const float* __restrict__ P,
                                               const int* __restrict__ pos,
                                               unsigned short* __restrict__ q_full){
  int t = blockIdx.x, tid = threadIdx.x;
  const float* r0 = P + (size_t)t*N_QB;
  const float* r1 = r0 + (size_t)T*N_QB;
  float p = (float)pos[t];
  for (int idx = tid; idx < NH*160; idx += 256){
    int h = idx/160, j = idx - h*160;
    if (j < 128){
      float v = (r0[h*QK_HD + j] + r1[h*QK_HD + j]) * ATT_SCALE;
      q_full[((size_t)(h*T + t))*QK_HD + j] = f2bf(v);
    } else {
      int i = j - 128;
      int d0 = D_NOPE + 2*i;
      float x1 = r0[h*QK_HD + d0]   + r1[h*QK_HD + d0];
      float x2 = r0[h*QK_HD + d0+1] + r1[h*QK_HD + d0+1];
      float invf = 1.0f / powf(10000.0f, (float)(2*i)/64.0f);
      float sn, cs; sincosf(p*invf, &sn, &cs);
      unsigned short* qr = q_full + ((size_t)(h*T + t))*QK_HD + d0;
      qr[0] = f2bf((x1*cs - x2*sn)*ATT_SCALE);
      qr[1] = f2bf((x2*cs + x1*sn)*ATT_SCALE);
    }
  }
}

// ---------------- RMSNorm qkva[:, :1536] -> q_c bf16 ----------------
__global__ __launch_bounds__(256) void k_rms_q(const float* __restrict__ qkva,
                                               const float* __restrict__ w,
                                               unsigned short* __restrict__ qc){
  int t = blockIdx.x, tid = threadIdx.x;
  const float* row = qkva + (size_t)t*N_QKVA;
  float ss = 0.f;
  for (int i = tid; i < Q_LORA; i += 256){ float x = row[i]; ss += x*x; }
  #pragma unroll
  for (int off=1; off<64; off<<=1) ss += __shfl_xor(ss, off, 64);
  __shared__ float red[4];
  if ((tid & 63) == 0) red[tid>>6] = ss;
  __syncthreads();
  ss = red[0]+red[1]+red[2]+red[3];
  float sc = rsqrtf(ss/(float)Q_LORA + 1e-6f);
  unsigned short* orow = qc + (size_t)t*Q_LORA;
  for (int i = tid; i < Q_LORA; i += 256) orow[i] = f2bf(row[i]*sc*w[i]);
}

// ------ RMSNorm qkva[:, 1536:2048] -> kv_c ; rope(qkva[:, 2048:2112]) -> k_full rope ------
__global__ __launch_bounds__(256) void k_rms_kv(const float* __restrict__ qkva,
                                                const float* __restrict__ w,
                                                const int* __restrict__ pos,
                                                unsigned short* __restrict__ kvc,
                                                unsigned short* __restrict__ k_full){
  int t = blockIdx.x, tid = threadIdx.x;
  const float* row = qkva + (size_t)t*N_QKVA + Q_LORA;
  float ss = 0.f;
  for (int i = tid; i < KV_LORA; i += 256){ float x = row[i]; ss += x*x; }
  #pragma unroll
  for (int off=1; off<64; off<<=1) ss += __shfl_xor(ss, off, 64);
  __shared__ float red[4];
  if ((tid & 63) == 0) red[tid>>6] = ss;
  __syncthreads();
  ss = red[0]+red[1]+red[2]+red[3];
  float sc = rsqrtf(ss/(float)KV_LORA + 1e-6f);
  for (int i = tid; i < KV_LORA; i += 256)
    kvc[(size_t)t*KV_LORA + i] = f2bf(row[i]*sc*w[i]);
  if (tid < 32){
    int i = tid;
    float x1 = row[KV_LORA + 2*i], x2 = row[KV_LORA + 2*i + 1];
    float p = (float)pos[t];
    float invf = 1.0f / powf(10000.0f, (float)(2*i)/64.0f);
    float sn, cs; sincosf(p*invf, &sn, &cs);
    unsigned short b1 = f2bf(x1*cs - x2*sn), b2 = f2bf(x2*cs + x1*sn);
    for (int h=0; h<NH; ++h){
      unsigned short* kr = k_full + ((size_t)(h*T + t))*QK_HD + D_NOPE + 2*i;
      kr[0] = b1; kr[1] = b2;
    }
  }
}

// -------- scatter kv_up: k_nope -> k_full[h][t][0:128]; v -> vt[h][d][t] (transposed) -----
__global__ __launch_bounds__(256) void k_scat_kv(const float* __restrict__ kvup,
                                                 unsigned short* __restrict__ k_full,
                                                 unsigned short* __restrict__ vt){
  int h = blockIdx.y, t0 = blockIdx.x*32;
  int tid = threadIdx.x;
  __shared__ float vtile[32][129];
  #pragma unroll
  for (int it=0; it<16; ++it){
    int idx = tid + it*256;
    int r = idx >> 7, d = idx & 127;
    float kn = kvup[(size_t)(t0 + r)*N_KVB + h*256 + d];
    k_full[((size_t)(h*T + t0 + r))*QK_HD + d] = f2bf(kn);
    vtile[r][d] = kvup[(size_t)(t0 + r)*N_KVB + h*256 + 128 + d];
  }
  __syncthreads();
  int d = tid >> 1, half = tid & 1;
  unsigned short* vrow = vt + ((size_t)(h*128 + d))*T + t0 + half*16;
  #pragma unroll
  for (int c=0; c<4; ++c){
    u16x4 o;
    o.x = f2bf(vtile[half*16 + c*4 + 0][d]);
    o.y = f2bf(vtile[half*16 + c*4 + 1][d]);
    o.z = f2bf(vtile[half*16 + c*4 + 2][d]);
    o.w = f2bf(vtile[half*16 + c*4 + 3][d]);
    *(u16x4*)(vrow + c*4) = o;
  }
}

// ------- flash attention, paired-causal, 4 waves, K-dbuf LDS + V reg-prefetch -------
__global__ __launch_bounds__(256,1) void k_attn(const unsigned short* __restrict__ q_full,
                                                const unsigned short* __restrict__ k_full,
                                                const unsigned short* __restrict__ vt,
                                                unsigned short* __restrict__ attn){
  __shared__ unsigned short K_lds[2][3*64*8*8];   // 2 x 24 KB
  __shared__ unsigned short P_t[4][16][68];
  int bid = blockIdx.x;
  int h  = ((bid & 7) << 1) | ((bid >> 3) & 1);   // 2 heads per XCD
  int qp = bid >> 4;                              // 0..15
  int qtA = qp, qtB = 31 - qp;
  int ntiles = qtB + 1;                           // 17..32
  int tid = threadIdx.x, w = tid >> 6, l = tid & 63, lr = l & 15, lg = l >> 4;
  int qrowA = qtA*64 + w*16 + lr;
  int qrowB = qtB*64 + w*16 + lr;
  BF8 qfA[6], qfB[6];
  {
    const unsigned short* qa = q_full + ((size_t)(h*T + qrowA))*QK_HD + 8*lg;
    const unsigned short* qb = q_full + ((size_t)(h*T + qrowB))*QK_HD + 8*lg;
    #pragma unroll
    for (int dk=0; dk<6; ++dk){
      qfA[dk].q = *(const u32x4*)(qa + dk*32);
      qfB[dk].q = *(const u32x4*)(qb + dk*32);
    }
  }
  float mA = -1e30f, lA = 0.f, mB = -1e30f, lB = 0.f;
  f32x4_t z4 = {0.f,0.f,0.f,0.f};
  f32x4_t oA[8], oB[8];
  #pragma unroll
  for (int i=0;i<8;i++){ oA[i] = z4; oB[i] = z4; }

  const unsigned short* kbase = k_full + (size_t)h*T*QK_HD;
  auto stageK = [&](int b, int t){
    #pragma unroll
    for (int is=0; is<6; ++is){
      int c = is*256 + tid;
      int chunk3 = c >> 9, row = (c >> 3) & 63, slot = c & 7;
      gload_lds16(kbase + (size_t)(t*64 + row)*QK_HD + chunk3*64 + ((slot ^ (row & 7))*8),
                  &K_lds[b][c*8]);
    }
  };
  stageK(0, 0);
  __syncthreads();
  int p = 0;
  int pslot0 = lg ^ (lr & 7), pslot1 = (4 + lg) ^ (lr & 7);
  for (int t = 0; t < ntiles; ++t){
    int s0 = t*64;
    BF8 va[8][2];
    #pragma unroll
    for (int df=0; df<8; ++df){
      const unsigned short* vp = vt + ((size_t)(h*D_V + df*16 + lr))*T + s0 + 8*lg;
      va[df][0].q = *(const u32x4*)(vp);
      va[df][1].q = *(const u32x4*)(vp + 32);
    }
    if (t+1 < ntiles) stageK(p^1, t+1);
    bool actA = (t <= qtA);
    f32x4_t sA[4], sB[4];
    #pragma unroll
    for (int i=0;i<4;i++){ sA[i] = z4; sB[i] = z4; }
    #pragma unroll
    for (int sfi=0; sfi<4; ++sfi){
      int rbase = (sfi*16 + lr)*8;
      #pragma unroll
      for (int dk=0; dk<6; ++dk){
        int ps = (dk & 1) ? pslot1 : pslot0;
        BF8 a; a.q = *(const u32x4*)&K_lds[p][(((dk>>1)*64*8) + rbase + ps)*8];
        sB[sfi] = __builtin_amdgcn_mfma_f32_16x16x32_bf16(a.v, qfB[dk].v, sB[sfi], 0,0,0);
        if (actA)
          sA[sfi] = __builtin_amdgcn_mfma_f32_16x16x32_bf16(a.v, qfA[dk].v, sA[sfi], 0,0,0);
      }
    }
    {
      bool diag = (t == ntiles-1);
      float tmax = -1e30f;
      #pragma unroll
      for (int sfi=0; sfi<4; ++sfi){
        #pragma unroll
        for (int rg=0; rg<4; ++rg){
          int s_g = s0 + sfi*16 + 4*lg + rg;
          float v = sB[sfi][rg];
          if (diag && s_g > qrowB) v = -1e30f;
          sB[sfi][rg] = v;
          tmax = fmaxf(tmax, v);
        }
      }
      tmax = fmaxf(tmax, __shfl_xor(tmax, 16, 64));
      tmax = fmaxf(tmax, __shfl_xor(tmax, 32, 64));
      float m_new = fmaxf(mB, tmax);
      float alpha = __expf(mB - m_new);
      float psum = 0.f;
      #pragma unroll
      for (int sfi=0; sfi<4; ++sfi){
        #pragma unroll
        for (int rg=0; rg<4; ++rg){
          float pv = __expf(sB[sfi][rg] - m_new);
          psum += pv;
          P_t[w][lr][sfi*16 + 4*lg + rg] = f2bf(pv);
        }
      }
      psum += __shfl_xor(psum, 16, 64);
      psum += __shfl_xor(psum, 32, 64);
      lB = lB*alpha + psum;
      mB = m_new;
      BF8 bp[2];
      #pragma unroll
      for (int ks=0; ks<2; ++ks){
        bp[ks].h[0] = *(const u16x4*)&P_t[w][lr][ks*32 + 8*lg];
        bp[ks].h[1] = *(const u16x4*)&P_t[w][lr][ks*32 + 8*lg + 4];
      }
      #pragma unroll
      for (int df=0; df<8; ++df){
        oB[df][0]*=alpha; oB[df][1]*=alpha; oB[df][2]*=alpha; oB[df][3]*=alpha;
        oB[df] = __builtin_amdgcn_mfma_f32_16x16x32_bf16(va[df][0].v, bp[0].v, oB[df], 0,0,0);
        oB[df] = __builtin_amdgcn_mfma_f32_16x16x32_bf16(va[df][1].v, bp[1].v, oB[df], 0,0,0);
      }
    }
    if (actA){
      bool diag = (t == qtA);
      float tmax = -1e30f;
      #pragma unroll
      for (int sfi=0; sfi<4; ++sfi){
        #pragma unroll
        for (int rg=0; rg<4; ++rg){
          int s_g = s0 + sfi*16 + 4*lg + rg;
          float v = sA[sfi][rg];
          if (diag && s_g > qrowA) v = -1e30f;
          sA[sfi][rg] = v;
          tmax = fmaxf(tmax, v);
        }
      }
      tmax = fmaxf(tmax, __shfl_xor(tmax, 16, 64));
      tmax = fmaxf(tmax, __shfl_xor(tmax, 32, 64));
      float m_new = fmaxf(mA, tmax);
      float alpha = __expf(mA - m_new);
      float psum = 0.f;
      #pragma unroll
      for (int sfi=0; sfi<4; ++sfi){
        #pragma unroll
        for (int rg=0; rg<4; ++rg){
          float pv = __expf(sA[sfi][rg] - m_new);
          psum += pv;
          P_t[w][lr][sfi*16 + 4*lg + rg] = f2bf(pv);
        }
      }
      psum += __shfl_xor(psum, 16, 64);
      psum += __shfl_xor(psum, 32, 64);
      lA = lA*alpha + psum;
      mA = m_new;
      BF8 bp[2];
      #pragma unroll
      for (int ks=0; ks<2; ++ks){
        bp[ks].h[0] = *(const u16x4*)&P_t[w][lr][ks*32 + 8*lg];
        bp[ks].h[1] = *(const u16x4*)&P_t[w][lr][ks*32 + 8*lg + 4];
      }
      #pragma unroll
      for (int df=0; df<8; ++df){
        oA[df][0]*=alpha; oA[df][1]*=alpha; oA[df][2]*=alpha; oA[df][3]*=alpha;
        oA[df] = __builtin_amdgcn_mfma_f32_16x16x32_bf16(va[df][0].v, bp[0].v, oA[df], 0,0,0);
        oA[df] = __builtin_amdgcn_mfma_f32_16x16x32_bf16(va[df][1].v, bp[1].v, oA[df], 0,0,0);
      }
    }
    __syncthreads();
    p ^= 1;
  }
  float invA = 1.0f / lA, invB = 1.0f / lB;
  #pragma unroll
  for (int df=0; df<8; ++df){
    u16x4 ov;
    ov.x = f2bf(oA[df][0]*invA); ov.y = f2bf(oA[df][1]*invA);
    ov.z = f2bf(oA[df][2]*invA); ov.w = f2bf(oA[df][3]*invA);
    *(u16x4*)(attn + (size_t)qrowA*(NH*D_V) + h*D_V + df*16 + 4*lg) = ov;
    ov.x = f2bf(oB[df][0]*invB); ov.y = f2bf(oB[df][1]*invB);
    ov.z = f2bf(oB[df][2]*invB); ov.w = f2bf(oB[df][3]*invB);
    *(u16x4*)(attn + (size_t)qrowB*(NH*D_V) + h*D_V + df*16 + 4*lg) = ov;
  }
}

extern "C" void kernel_launch(void* const* d_in, const int* in_sizes, int n_in,
                              void* d_out, int out_size, void* d_ws, size_t ws_size,
                              hipStream_t stream){
  const int*   positions = (const int*)d_in[0];
  const float* hidden = (const float*)d_in[1];
  const float* w_qa   = (const float*)d_in[2];
  const float* qa_ln  = (const float*)d_in[3];
  const float* w_qb   = (const float*)d_in[4];
  const float* w_kva  = (const float*)d_in[5];
  const float* kva_ln = (const float*)d_in[6];
  const float* w_kvb  = (const float*)d_in[7];
  const float* w_o    = (const float*)d_in[8];
  float* out = (float*)d_out;

  char* p = (char*)d_ws;
  auto alloc = [&](size_t bytes){ void* r = (void*)p; p += (bytes + 255) & ~(size_t)255; return r; };
  unsigned short* hb      = (unsigned short*)alloc((size_t)T*HID*2);
  unsigned short* wqkvaT  = (unsigned short*)alloc((size_t)N_QKVA*HID*2);
  unsigned short* wqbT    = (unsigned short*)alloc((size_t)N_QB*Q_LORA*2);
  unsigned short* wkvbT   = (unsigned short*)alloc((size_t)N_KVB*KV_LORA*2);
  unsigned short* woT     = (unsigned short*)alloc((size_t)HID*(NH*D_V)*2);
  float* qkva             = (float*)alloc((size_t)T*N_QKVA*4);
  unsigned short* q_c     = (unsigned short*)alloc((size_t)T*Q_LORA*2);
  unsigned short* kv_c    = (unsigned short*)alloc((size_t)T*KV_LORA*2);
  unsigned short* q_full  = (unsigned short*)alloc((size_t)NH*T*QK_HD*2);
  unsigned short* k_full  = (unsigned short*)alloc((size_t)NH*T*QK_HD*2);
  unsigned short* vt      = (unsigned short*)alloc((size_t)NH*D_V*T*2);
  unsigned short* attnb   = (unsigned short*)alloc((size_t)T*NH*D_V*2);
  float* Pbuf             = (float*)alloc((size_t)3*T*N_QKVA*4);  // 56 MB, reused
  float* kvupf            = Pbuf;   // alias: KVB output after Pbuf's last use

  k_cvt<<<2048, 256, 0, stream>>>(hidden, hb, T*HID/4);
  // merged weight: rows [0,1536) = w_qa^T, rows [1536,2176) = w_kva^T (pad 576->640)
  k_cvtT<<<dim3(Q_LORA/32, HID/32), 256, 0, stream>>>(w_qa, wqkvaT, HID, Q_LORA);
  k_cvtT<<<dim3(KVA_NP/32, HID/32), 256, 0, stream>>>(w_kva, wqkvaT + (size_t)Q_LORA*HID, HID, KVA_N);
  k_cvtT<<<dim3(N_QB/32, Q_LORA/32), 256, 0, stream>>>(w_qb, wqbT, Q_LORA, N_QB);
  k_cvtT<<<dim3(N_KVB/32, KV_LORA/32), 256, 0, stream>>>(w_kvb, wkvbT, KV_LORA, N_KVB);
  k_cvtT<<<dim3(HID/32, (NH*D_V)/32), 256, 0, stream>>>(w_o, woT, NH*D_V, HID);

  // merged QA+KVA, split-K S=3 (816 blocks)
  k_gemm<<<dim3(N_QKVA/128, T/128, 3), 256, 0, stream>>>(hb, wqkvaT, Pbuf, T, N_QKVA, HID, 1728);
  k_red3<<<1024, 256, 0, stream>>>(Pbuf, qkva, T*N_QKVA/4);
  k_rms_q<<<T, 256, 0, stream>>>(qkva, qa_ln, q_c);
  k_rms_kv<<<T, 256, 0, stream>>>(qkva, kva_ln, positions, kv_c, k_full);
  // QB, split-K S=2 (768 blocks); reduce fuses scale+rope -> q_full
  k_gemm<<<dim3(N_QB/128, T/128, 2), 256, 0, stream>>>(q_c, wqbT, Pbuf, T, N_QB, Q_LORA, 768);
  k_red_q<<<T, 256, 0, stream>>>(Pbuf, positions, q_full);
  // KVB direct (512 blocks) -> kvupf (aliases Pbuf, previous use complete)
  k_gemm<<<dim3(N_KVB/128, T/128, 1), 256, 0, stream>>>(kv_c, wkvbT, kvupf, T, N_KVB, KV_LORA, KV_LORA);
  k_scat_kv<<<dim3(T/32, NH), 256, 0, stream>>>(kvupf, k_full, vt);
  k_attn<<<256, 256, 0, stream>>>(q_full, k_full, vt, attnb);
  // O-proj direct (640 blocks) -> out fp32
  k_gemm<<<dim3(HID/128, T/128, 1), 256, 0, stream>>>(attnb, woT, out, T, HID, NH*D_V, NH*D_V);
}

// Round 6
// 572.575 us; speedup vs baseline: 1.4065x; 1.0174x over previous
//
#include <hip/hip_runtime.h>
#include <hip/hip_bf16.h>
#include <math.h>

#define T 2048
#define HID 5120
#define NH 16
#define D_NOPE 128
#define D_ROPE 64
#define D_V 128
#define Q_LORA 1536
#define KV_LORA 512
#define QK_HD 192
#define KVA_N 576
#define KVA_NP 640
#define N_QKVA (Q_LORA + KVA_NP)  // 2176
#define N_QB (NH*QK_HD)          // 3072
#define N_KVB (NH*(D_NOPE+D_V))  // 4096
#define ATT_SCALE 0.07216878364870322f  // 192^-0.5

typedef __bf16 bf16x8_t __attribute__((ext_vector_type(8)));
typedef float f32x4_t __attribute__((ext_vector_type(4)));
typedef unsigned short u16x4 __attribute__((ext_vector_type(4)));
typedef unsigned int u32x4 __attribute__((ext_vector_type(4)));

union BF8 { u16x4 h[2]; unsigned short u[8]; bf16x8_t v; u32x4 q; };

static __device__ __forceinline__ unsigned short f2bf(float f){
  union { float f; unsigned u; } x; x.f = f;
  unsigned r = x.u + 0x7FFFu + ((x.u >> 16) & 1u);
  return (unsigned short)(r >> 16);
}

// async global->LDS, 16B per lane. LDS dest = wave-uniform base + lane*16.
static __device__ __forceinline__ void gload_lds16(const void* g, void* l){
  __builtin_amdgcn_global_load_lds(
      (const __attribute__((address_space(1))) void*)(unsigned long long)g,
      (__attribute__((address_space(3))) void*)(unsigned int)(unsigned long long)l,
      16, 0, 0);
}

// ---------------- fp32 -> bf16 (no transpose) ----------------
__global__ __launch_bounds__(256) void k_cvt(const float* __restrict__ in,
                                             unsigned short* __restrict__ out, int n4){
  int i = blockIdx.x*256 + threadIdx.x;
  int stride = gridDim.x*256;
  for (; i < n4; i += stride){
    f32x4_t v = ((const f32x4_t*)in)[i];
    u16x4 o; o.x=f2bf(v.x); o.y=f2bf(v.y); o.z=f2bf(v.z); o.w=f2bf(v.w);
    ((u16x4*)out)[i] = o;
  }
}

// ---------------- fp32 W[K][N] -> bf16 Wt[Npad][K] (transpose, zero pad rows >= N) --------
__global__ __launch_bounds__(256) void k_cvtT(const float* __restrict__ W,
                                              unsigned short* __restrict__ Wt, int K, int N){
  __shared__ float tile[32][33];
  int n0 = blockIdx.x*32, k0 = blockIdx.y*32;
  int r = threadIdx.x >> 3, c4 = (threadIdx.x & 7) * 4;
  f32x4_t v = {0.f,0.f,0.f,0.f};
  if (n0 + c4 < N) v = *(const f32x4_t*)(W + (size_t)(k0 + r)*N + n0 + c4);
  tile[r][c4+0]=v.x; tile[r][c4+1]=v.y; tile[r][c4+2]=v.z; tile[r][c4+3]=v.w;
  __syncthreads();
  u16x4 o;
  o.x = f2bf(tile[c4+0][r]); o.y = f2bf(tile[c4+1][r]);
  o.z = f2bf(tile[c4+2][r]); o.w = f2bf(tile[c4+3][r]);
  *(u16x4*)(Wt + (size_t)(n0 + r)*K + k0 + c4) = o;
}

// ---- GEMM (m97 structure + split-K + XCD swizzle) ----
__global__ __launch_bounds__(256) void k_gemm(const unsigned short* __restrict__ A,
                                              const unsigned short* __restrict__ Bt,
                                              float* __restrict__ C,
                                              int M, int N, int K, int kChunk){
  __shared__ unsigned short sA[128*32];
  __shared__ unsigned short sB[128*32];
  int gx = gridDim.x;
  int nwg = gx*gridDim.y;
  int id = blockIdx.x + gx*blockIdx.y;
  int cpx = nwg >> 3;
  int swz = (id & 7)*cpx + (id >> 3);     // bijective when nwg%8==0
  int bn = (swz % gx)*128, bm = (swz / gx)*128;
  int kBeg = blockIdx.z*kChunk;
  int kEnd = kBeg + kChunk; if (kEnd > K) kEnd = K;
  float* Cs = C + (size_t)blockIdx.z*M*N;
  int tid = threadIdx.x;
  int l = tid & 63, lr = l & 15, lg = l >> 4;
  int w = tid >> 6;
  int wm = (w >> 1)*64, wn = (w & 1)*64;
  f32x4_t acc[4][4];
  f32x4_t z4 = {0.f,0.f,0.f,0.f};
  #pragma unroll
  for (int i=0;i<4;i++)
    #pragma unroll
    for(int j=0;j<4;j++) acc[i][j] = z4;
  for (int k0 = kBeg; k0 < kEnd; k0 += 32){
    __syncthreads();
    #pragma unroll
    for (int it = 0; it < 2; ++it){
      int c = it*256 + tid;
      int row = c >> 2, kc = (c & 3) * 8;
      gload_lds16(A  + (size_t)(bm + row)*K + k0 + kc, &sA[c*8]);
      gload_lds16(Bt + (size_t)(bn + row)*K + k0 + kc, &sB[c*8]);
    }
    __syncthreads();
    BF8 af[4], bf[4];
    #pragma unroll
    for (int mf=0; mf<4; ++mf)
      af[mf].q = *(const u32x4*)&sA[(wm + mf*16 + lr)*32 + 8*lg];
    #pragma unroll
    for (int nf=0; nf<4; ++nf)
      bf[nf].q = *(const u32x4*)&sB[(wn + nf*16 + lr)*32 + 8*lg];
    #pragma unroll
    for (int mf=0; mf<4; ++mf)
      #pragma unroll
      for (int nf=0; nf<4; ++nf)
        acc[mf][nf] = __builtin_amdgcn_mfma_f32_16x16x32_bf16(af[mf].v, bf[nf].v, acc[mf][nf], 0,0,0);
  }
  #pragma unroll
  for (int mf=0; mf<4; ++mf){
    int row = bm + wm + mf*16 + 4*lg;
    #pragma unroll
    for (int nf=0; nf<4; ++nf){
      int col = bn + wn + nf*16 + lr;
      #pragma unroll
      for (int rg=0; rg<4; ++rg)
        Cs[(size_t)(row + rg)*N + col] = acc[mf][nf][rg];
    }
  }
}

// ---------------- reduce 3 split-K slices of [T][2176] -> qkva fp32 ----------------
__global__ __launch_bounds__(256) void k_red3(const float* __restrict__ P,
                                              float* __restrict__ out, int n4){
  const size_t sstr = (size_t)T*N_QKVA/4;
  int i = blockIdx.x*256 + threadIdx.x, stride = gridDim.x*256;
  const f32x4_t* p4 = (const f32x4_t*)P;
  f32x4_t* o4 = (f32x4_t*)out;
  for (; i < n4; i += stride)
    o4[i] = p4[i] + p4[i+sstr] + p4[i+2*sstr];
}

// ------- reduce 2 split-K slices of QB output + scale/rope -> q_full bf16 [h][t][192] ----
__global__ __launch_bounds__(256) void k_red_q(const float* __restrict__ P,
                                               const int* __restrict__ pos,
                                               unsigned short* __restrict__ q_full){
  int t = blockIdx.x, tid = threadIdx.x;
  const float* r0 = P + (size_t)t*N_QB;
  const float* r1 = r0 + (size_t)T*N_QB;
  float p = (float)pos[t];
  for (int idx = tid; idx < NH*160; idx += 256){
    int h = idx/160, j = idx - h*160;
    if (j < 128){
      float v = (r0[h*QK_HD + j] + r1[h*QK_HD + j]) * ATT_SCALE;
      q_full[((size_t)(h*T + t))*QK_HD + j] = f2bf(v);
    } else {
      int i = j - 128;
      int d0 = D_NOPE + 2*i;
      float x1 = r0[h*QK_HD + d0]   + r1[h*QK_HD + d0];
      float x2 = r0[h*QK_HD + d0+1] + r1[h*QK_HD + d0+1];
      float invf = 1.0f / powf(10000.0f, (float)(2*i)/64.0f);
      float sn, cs; sincosf(p*invf, &sn, &cs);
      unsigned short* qr = q_full + ((size_t)(h*T + t))*QK_HD + d0;
      qr[0] = f2bf((x1*cs - x2*sn)*ATT_SCALE);
      qr[1] = f2bf((x2*cs + x1*sn)*ATT_SCALE);
    }
  }
}

// ---------------- RMSNorm qkva[:, :1536] -> q_c bf16 ----------------
__global__ __launch_bounds__(256) void k_rms_q(const float* __restrict__ qkva,
                                               const float* __restrict__ w,
                                               unsigned short* __restrict__ qc){
  int t = blockIdx.x, tid = threadIdx.x;
  const float* row = qkva + (size_t)t*N_QKVA;
  float ss = 0.f;
  for (int i = tid; i < Q_LORA; i += 256){ float x = row[i]; ss += x*x; }
  #pragma unroll
  for (int off=1; off<64; off<<=1) ss += __shfl_xor(ss, off, 64);
  __shared__ float red[4];
  if ((tid & 63) == 0) red[tid>>6] = ss;
  __syncthreads();
  ss = red[0]+red[1]+red[2]+red[3];
  float sc = rsqrtf(ss/(float)Q_LORA + 1e-6f);
  unsigned short* orow = qc + (size_t)t*Q_LORA;
  for (int i = tid; i < Q_LORA; i += 256) orow[i] = f2bf(row[i]*sc*w[i]);
}

// ------ RMSNorm qkva[:, 1536:2048] -> kv_c ; rope(qkva[:, 2048:2112]) -> k_full rope ------
__global__ __launch_bounds__(256) void k_rms_kv(const float* __restrict__ qkva,
                                                const float* __restrict__ w,
                                                const int* __restrict__ pos,
                                                unsigned short* __restrict__ kvc,
                                                unsigned short* __restrict__ k_full){
  int t = blockIdx.x, tid = threadIdx.x;
  const float* row = qkva + (size_t)t*N_QKVA + Q_LORA;
  float ss = 0.f;
  for (int i = tid; i < KV_LORA; i += 256){ float x = row[i]; ss += x*x; }
  #pragma unroll
  for (int off=1; off<64; off<<=1) ss += __shfl_xor(ss, off, 64);
  __shared__ float red[4];
  if ((tid & 63) == 0) red[tid>>6] = ss;
  __syncthreads();
  ss = red[0]+red[1]+red[2]+red[3];
  float sc = rsqrtf(ss/(float)KV_LORA + 1e-6f);
  for (int i = tid; i < KV_LORA; i += 256)
    kvc[(size_t)t*KV_LORA + i] = f2bf(row[i]*sc*w[i]);
  if (tid < 32){
    int i = tid;
    float x1 = row[KV_LORA + 2*i], x2 = row[KV_LORA + 2*i + 1];
    float p = (float)pos[t];
    float invf = 1.0f / powf(10000.0f, (float)(2*i)/64.0f);
    float sn, cs; sincosf(p*invf, &sn, &cs);
    unsigned short b1 = f2bf(x1*cs - x2*sn), b2 = f2bf(x2*cs + x1*sn);
    for (int h=0; h<NH; ++h){
      unsigned short* kr = k_full + ((size_t)(h*T + t))*QK_HD + D_NOPE + 2*i;
      kr[0] = b1; kr[1] = b2;
    }
  }
}

// -------- scatter kv_up: k_nope -> k_full[h][t][0:128]; v -> vt[h][d][t] (transposed) -----
__global__ __launch_bounds__(256) void k_scat_kv(const float* __restrict__ kvup,
                                                 unsigned short* __restrict__ k_full,
                                                 unsigned short* __restrict__ vt){
  int h = blockIdx.y, t0 = blockIdx.x*32;
  int tid = threadIdx.x;
  __shared__ float vtile[32][129];
  #pragma unroll
  for (int it=0; it<16; ++it){
    int idx = tid + it*256;
    int r = idx >> 7, d = idx & 127;
    float kn = kvup[(size_t)(t0 + r)*N_KVB + h*256 + d];
    k_full[((size_t)(h*T + t0 + r))*QK_HD + d] = f2bf(kn);
    vtile[r][d] = kvup[(size_t)(t0 + r)*N_KVB + h*256 + 128 + d];
  }
  __syncthreads();
  int d = tid >> 1, half = tid & 1;
  unsigned short* vrow = vt + ((size_t)(h*128 + d))*T + t0 + half*16;
  #pragma unroll
  for (int c=0; c<4; ++c){
    u16x4 o;
    o.x = f2bf(vtile[half*16 + c*4 + 0][d]);
    o.y = f2bf(vtile[half*16 + c*4 + 1][d]);
    o.z = f2bf(vtile[half*16 + c*4 + 2][d]);
    o.w = f2bf(vtile[half*16 + c*4 + 3][d]);
    *(u16x4*)(vrow + c*4) = o;
  }
}

// ------- flash attention: 512 blocks (16 heads x 32 q-tiles), 4 waves, K-dbuf + V reg-prefetch
// 2 blocks/CU co-resident (113 KB LDS) -> 2 waves/SIMD for cross-block latency hiding.
// bids 0..255 = heavy halves (qt 31..16) dispatched first, 256..511 = light (qt 15..0).
__global__ __launch_bounds__(256,2) void k_attn(const unsigned short* __restrict__ q_full,
                                                const unsigned short* __restrict__ k_full,
                                                const unsigned short* __restrict__ vt,
                                                unsigned short* __restrict__ attn){
  __shared__ unsigned short K_lds[2][3*64*8*8];   // 2 x 24 KB
  __shared__ unsigned short P_t[4][16][68];
  int bid = blockIdx.x;
  int half = bid >> 8, r = bid & 255;
  int h  = ((r & 7) << 1) | ((r >> 3) & 1);       // 2 heads per XCD
  int qidx = r >> 4;                              // 0..15
  int qt = half ? (15 - qidx) : (31 - qidx);
  int ntiles = qt + 1;
  int tid = threadIdx.x, w = tid >> 6, l = tid & 63, lr = l & 15, lg = l >> 4;
  int qrow = qt*64 + w*16 + lr;
  BF8 qf[6];
  {
    const unsigned short* qp = q_full + ((size_t)(h*T + qrow))*QK_HD + 8*lg;
    #pragma unroll
    for (int dk=0; dk<6; ++dk) qf[dk].q = *(const u32x4*)(qp + dk*32);
  }
  float m_run = -1e30f, l_run = 0.f;
  f32x4_t z4 = {0.f,0.f,0.f,0.f};
  f32x4_t o[8];
  #pragma unroll
  for (int i=0;i<8;i++) o[i] = z4;

  const unsigned short* kbase = k_full + (size_t)h*T*QK_HD;
  auto stageK = [&](int b, int t){
    #pragma unroll
    for (int is=0; is<6; ++is){
      int c = is*256 + tid;
      int chunk3 = c >> 9, row = (c >> 3) & 63, slot = c & 7;
      gload_lds16(kbase + (size_t)(t*64 + row)*QK_HD + chunk3*64 + ((slot ^ (row & 7))*8),
                  &K_lds[b][c*8]);
    }
  };
  stageK(0, 0);
  __syncthreads();
  int p = 0;
  int pslot0 = lg ^ (lr & 7), pslot1 = (4 + lg) ^ (lr & 7);
  for (int t = 0; t < ntiles; ++t){
    int s0 = t*64;
    // V register prefetch (T14): issued early, consumed in PV
    BF8 va[8][2];
    #pragma unroll
    for (int df=0; df<8; ++df){
      const unsigned short* vp = vt + ((size_t)(h*D_V + df*16 + lr))*T + s0 + 8*lg;
      va[df][0].q = *(const u32x4*)(vp);
      va[df][1].q = *(const u32x4*)(vp + 32);
    }
    if (t+1 < ntiles) stageK(p^1, t+1);
    // ---- QK^T ----
    f32x4_t sf[4];
    #pragma unroll
    for (int i=0;i<4;i++) sf[i] = z4;
    __builtin_amdgcn_s_setprio(1);
    #pragma unroll
    for (int sfi=0; sfi<4; ++sfi){
      int rbase = (sfi*16 + lr)*8;
      #pragma unroll
      for (int dk=0; dk<6; ++dk){
        int ps = (dk & 1) ? pslot1 : pslot0;
        BF8 a; a.q = *(const u32x4*)&K_lds[p][(((dk>>1)*64*8) + rbase + ps)*8];
        sf[sfi] = __builtin_amdgcn_mfma_f32_16x16x32_bf16(a.v, qf[dk].v, sf[sfi], 0,0,0);
      }
    }
    __builtin_amdgcn_s_setprio(0);
    // ---- softmax (online, defer-max THR=8) ----
    bool diag = (t == ntiles-1);
    float tmax = -1e30f;
    #pragma unroll
    for (int sfi=0; sfi<4; ++sfi){
      #pragma unroll
      for (int rg=0; rg<4; ++rg){
        int s_g = s0 + sfi*16 + 4*lg + rg;
        float v = sf[sfi][rg];
        if (diag && s_g > qrow) v = -1e30f;
        sf[sfi][rg] = v;
        tmax = fmaxf(tmax, v);
      }
    }
    tmax = fmaxf(tmax, __shfl_xor(tmax, 16, 64));
    tmax = fmaxf(tmax, __shfl_xor(tmax, 32, 64));
    bool norescale = __all(tmax - m_run <= 8.0f);   // first tile: m_run=-1e30 -> false
    float alpha = 1.0f;
    if (!norescale){
      float m_new = fmaxf(m_run, tmax);
      alpha = __expf(m_run - m_new);
      m_run = m_new;
    }
    float psum = 0.f;
    #pragma unroll
    for (int sfi=0; sfi<4; ++sfi){
      #pragma unroll
      for (int rg=0; rg<4; ++rg){
        float pv = __expf(sf[sfi][rg] - m_run);
        psum += pv;
        P_t[w][lr][sfi*16 + 4*lg + rg] = f2bf(pv);
      }
    }
    psum += __shfl_xor(psum, 16, 64);
    psum += __shfl_xor(psum, 32, 64);
    l_run = l_run*alpha + psum;
    if (!norescale){
      #pragma unroll
      for (int i=0;i<8;i++){ o[i][0]*=alpha; o[i][1]*=alpha; o[i][2]*=alpha; o[i][3]*=alpha; }
    }
    // ---- PV ----
    BF8 bp[2];
    #pragma unroll
    for (int ks=0; ks<2; ++ks){
      bp[ks].h[0] = *(const u16x4*)&P_t[w][lr][ks*32 + 8*lg];
      bp[ks].h[1] = *(const u16x4*)&P_t[w][lr][ks*32 + 8*lg + 4];
    }
    __builtin_amdgcn_s_setprio(1);
    #pragma unroll
    for (int df=0; df<8; ++df){
      o[df] = __builtin_amdgcn_mfma_f32_16x16x32_bf16(va[df][0].v, bp[0].v, o[df], 0,0,0);
      o[df] = __builtin_amdgcn_mfma_f32_16x16x32_bf16(va[df][1].v, bp[1].v, o[df], 0,0,0);
    }
    __builtin_amdgcn_s_setprio(0);
    __syncthreads();
    p ^= 1;
  }
  float inv = 1.0f / l_run;
  #pragma unroll
  for (int df=0; df<8; ++df){
    u16x4 ov;
    ov.x = f2bf(o[df][0]*inv); ov.y = f2bf(o[df][1]*inv);
    ov.z = f2bf(o[df][2]*inv); ov.w = f2bf(o[df][3]*inv);
    *(u16x4*)(attn + (size_t)qrow*(NH*D_V) + h*D_V + df*16 + 4*lg) = ov;
  }
}

extern "C" void kernel_launch(void* const* d_in, const int* in_sizes, int n_in,
                              void* d_out, int out_size, void* d_ws, size_t ws_size,
                              hipStream_t stream){
  const int*   positions = (const int*)d_in[0];
  const float* hidden = (const float*)d_in[1];
  const float* w_qa   = (const float*)d_in[2];
  const float* qa_ln  = (const float*)d_in[3];
  const float* w_qb   = (const float*)d_in[4];
  const float* w_kva  = (const float*)d_in[5];
  const float* kva_ln = (const float*)d_in[6];
  const float* w_kvb  = (const float*)d_in[7];
  const float* w_o    = (const float*)d_in[8];
  float* out = (float*)d_out;

  char* p = (char*)d_ws;
  auto alloc = [&](size_t bytes){ void* r = (void*)p; p += (bytes + 255) & ~(size_t)255; return r; };
  unsigned short* hb      = (unsigned short*)alloc((size_t)T*HID*2);
  unsigned short* wqkvaT  = (unsigned short*)alloc((size_t)N_QKVA*HID*2);
  unsigned short* wqbT    = (unsigned short*)alloc((size_t)N_QB*Q_LORA*2);
  unsigned short* wkvbT   = (unsigned short*)alloc((size_t)N_KVB*KV_LORA*2);
  unsigned short* woT     = (unsigned short*)alloc((size_t)HID*(NH*D_V)*2);
  float* qkva             = (float*)alloc((size_t)T*N_QKVA*4);
  unsigned short* q_c     = (unsigned short*)alloc((size_t)T*Q_LORA*2);
  unsigned short* kv_c    = (unsigned short*)alloc((size_t)T*KV_LORA*2);
  unsigned short* q_full  = (unsigned short*)alloc((size_t)NH*T*QK_HD*2);
  unsigned short* k_full  = (unsigned short*)alloc((size_t)NH*T*QK_HD*2);
  unsigned short* vt      = (unsigned short*)alloc((size_t)NH*D_V*T*2);
  unsigned short* attnb   = (unsigned short*)alloc((size_t)T*NH*D_V*2);
  float* Pbuf             = (float*)alloc((size_t)3*T*N_QKVA*4);  // 56 MB, reused
  float* kvupf            = Pbuf;   // alias: KVB output after Pbuf's last use

  k_cvt<<<2048, 256, 0, stream>>>(hidden, hb, T*HID/4);
  // merged weight: rows [0,1536) = w_qa^T, rows [1536,2176) = w_kva^T (pad 576->640)
  k_cvtT<<<dim3(Q_LORA/32, HID/32), 256, 0, stream>>>(w_qa, wqkvaT, HID, Q_LORA);
  k_cvtT<<<dim3(KVA_NP/32, HID/32), 256, 0, stream>>>(w_kva, wqkvaT + (size_t)Q_LORA*HID, HID, KVA_N);
  k_cvtT<<<dim3(N_QB/32, Q_LORA/32), 256, 0, stream>>>(w_qb, wqbT, Q_LORA, N_QB);
  k_cvtT<<<dim3(N_KVB/32, KV_LORA/32), 256, 0, stream>>>(w_kvb, wkvbT, KV_LORA, N_KVB);
  k_cvtT<<<dim3(HID/32, (NH*D_V)/32), 256, 0, stream>>>(w_o, woT, NH*D_V, HID);

  // merged QA+KVA, split-K S=3 (816 blocks)
  k_gemm<<<dim3(N_QKVA/128, T/128, 3), 256, 0, stream>>>(hb, wqkvaT, Pbuf, T, N_QKVA, HID, 1728);
  k_red3<<<1024, 256, 0, stream>>>(Pbuf, qkva, T*N_QKVA/4);
  k_rms_q<<<T, 256, 0, stream>>>(qkva, qa_ln, q_c);
  k_rms_kv<<<T, 256, 0, stream>>>(qkva, kva_ln, positions, kv_c, k_full);
  // QB, split-K S=2 (768 blocks); reduce fuses scale+rope -> q_full
  k_gemm<<<dim3(N_QB/128, T/128, 2), 256, 0, stream>>>(q_c, wqbT, Pbuf, T, N_QB, Q_LORA, 768);
  k_red_q<<<T, 256, 0, stream>>>(Pbuf, positions, q_full);
  // KVB direct (512 blocks) -> kvupf (aliases Pbuf, previous use complete)
  k_gemm<<<dim3(N_KVB/128, T/128, 1), 256, 0, stream>>>(kv_c, wkvbT, kvupf, T, N_KVB, KV_LORA, KV_LORA);
  k_scat_kv<<<dim3(T/32, NH), 256, 0, stream>>>(kvupf, k_full, vt);
  k_attn<<<512, 256, 0, stream>>>(q_full, k_full, vt, attnb);
  // O-proj direct (640 blocks) -> out fp32
  k_gemm<<<dim3(HID/128, T/128, 1), 256, 0, stream>>>(attnb, woT, out, T, HID, NH*D_V, NH*D_V);
}